// Round 1
// baseline (1114.139 us; speedup 1.0000x reference)
//
#include <hip/hip_runtime.h>
#include <cmath>

#define HEADS 4
#define DD 32
#define FDIM 128   // H*D == IN_DIM == 128
#define NEG 0.2f

// ---------------------------------------------------------------------------
// feat = X @ W^T  (X: [N,128], W: [128,128] row-major, feat: [N,128])
// plus el[n,h] = sum_d feat[n,h,d]*al[h*32+d], er likewise.
// Block: 256 threads, 64 nodes. x staged transposed in LDS (stride 68 keeps
// float4 reads 16B-aligned; reads are broadcast so bank conflicts don't
// matter on the read side). Per-thread register tile: 4 f x 8 nodes.
// ---------------------------------------------------------------------------
__global__ __launch_bounds__(256) void gemm_elr_kernel(
    const float* __restrict__ X, const float* __restrict__ W,
    const float* __restrict__ al, const float* __restrict__ ar,
    float* __restrict__ feat, float* __restrict__ el, float* __restrict__ er,
    int nnodes)
{
    __shared__ float xsT[128 * 68];   // 34816 B
    const int tid = threadIdx.x;
    const int nb0 = blockIdx.x * 64;

    // stage X[nb0..nb0+63][0..127] -> xsT[k][n]
    #pragma unroll
    for (int j = 0; j < 8; ++j) {
        int fidx = tid + j * 256;          // 0..2047 float4 slots
        int n  = fidx >> 5;                // node within block
        int k4 = fidx & 31;                // float4 index along k
        float4 v = make_float4(0.f, 0.f, 0.f, 0.f);
        if (nb0 + n < nnodes)
            v = ((const float4*)X)[(size_t)(nb0 + n) * 32 + k4];
        xsT[(4 * k4 + 0) * 68 + n] = v.x;
        xsT[(4 * k4 + 1) * 68 + n] = v.y;
        xsT[(4 * k4 + 2) * 68 + n] = v.z;
        xsT[(4 * k4 + 3) * 68 + n] = v.w;
    }
    __syncthreads();

    const int fbase = (tid & 31) * 4;      // 4 consecutive output features
    const int nbase = (tid >> 5) * 8;      // 8 consecutive nodes

    float acc[4][8];
    #pragma unroll
    for (int a = 0; a < 4; ++a)
        #pragma unroll
        for (int b = 0; b < 8; ++b) acc[a][b] = 0.f;

    for (int kc = 0; kc < 128; kc += 8) {
        float wreg[4][8];
        #pragma unroll
        for (int ff = 0; ff < 4; ++ff) {
            float4 a = *(const float4*)&W[(fbase + ff) * 128 + kc];
            float4 b = *(const float4*)&W[(fbase + ff) * 128 + kc + 4];
            wreg[ff][0] = a.x; wreg[ff][1] = a.y; wreg[ff][2] = a.z; wreg[ff][3] = a.w;
            wreg[ff][4] = b.x; wreg[ff][5] = b.y; wreg[ff][6] = b.z; wreg[ff][7] = b.w;
        }
        #pragma unroll
        for (int k = 0; k < 8; ++k) {
            float4 x0 = *(const float4*)&xsT[(kc + k) * 68 + nbase];
            float4 x1 = *(const float4*)&xsT[(kc + k) * 68 + nbase + 4];
            float xv[8] = {x0.x, x0.y, x0.z, x0.w, x1.x, x1.y, x1.z, x1.w};
            #pragma unroll
            for (int ff = 0; ff < 4; ++ff)
                #pragma unroll
                for (int nn = 0; nn < 8; ++nn)
                    acc[ff][nn] += wreg[ff][k] * xv[nn];
        }
    }

    // write feat (float4: fbase..fbase+3 contiguous)
    #pragma unroll
    for (int nn = 0; nn < 8; ++nn) {
        int gn = nb0 + nbase + nn;
        if (gn < nnodes) {
            float4 v = make_float4(acc[0][nn], acc[1][nn], acc[2][nn], acc[3][nn]);
            *(float4*)&feat[(size_t)gn * 128 + fbase] = v;
        }
    }

    // el/er: partial over this thread's 4 f's, then width-8 shuffle reduce
    // (lanes 8h..8h+7 of each 32-lane group cover head h's 32 features)
    float alv[4], arv[4];
    #pragma unroll
    for (int ff = 0; ff < 4; ++ff) { alv[ff] = al[fbase + ff]; arv[ff] = ar[fbase + ff]; }

    float pel[8], per[8];
    #pragma unroll
    for (int nn = 0; nn < 8; ++nn) {
        float sl = 0.f, sr = 0.f;
        #pragma unroll
        for (int ff = 0; ff < 4; ++ff) {
            sl += acc[ff][nn] * alv[ff];
            sr += acc[ff][nn] * arv[ff];
        }
        pel[nn] = sl; per[nn] = sr;
    }
    #pragma unroll
    for (int off = 4; off >= 1; off >>= 1) {
        #pragma unroll
        for (int nn = 0; nn < 8; ++nn) {
            pel[nn] += __shfl_down(pel[nn], off, 8);
            per[nn] += __shfl_down(per[nn], off, 8);
        }
    }
    if ((tid & 7) == 0) {
        int h = (tid & 31) >> 3;
        #pragma unroll
        for (int nn = 0; nn < 8; ++nn) {
            int gn = nb0 + nbase + nn;
            if (gn < nnodes) {
                el[gn * HEADS + h] = pel[nn];
                er[gn * HEADS + h] = per[nn];
            }
        }
    }
}

// ---------------------------------------------------------------------------
// Edge pass: one thread per (edge, h, d). w = exp(leaky_relu(el[s]+er[d])).
// acc[dst,h,d] += w * feat[src,h,d]; denom[dst,h] += w.
// (max-subtraction skipped: e is O(1), exp safe in f32; result identical
//  after normalization)
// ---------------------------------------------------------------------------
__global__ __launch_bounds__(256) void edge_kernel(
    const float* __restrict__ feat, const float* __restrict__ el,
    const float* __restrict__ er, const int* __restrict__ src,
    const int* __restrict__ dst, float* __restrict__ acc,
    float* __restrict__ denom, int nedges)
{
    int gid = blockIdx.x * 256 + threadIdx.x;
    int edge = gid >> 7;
    if (edge >= nedges) return;
    int t = gid & 127;
    int h = t >> 5;
    int s = src[edge];
    int d = dst[edge];
    float e = el[s * HEADS + h] + er[d * HEADS + h];
    e = e > 0.f ? e : NEG * e;
    float w = __expf(e);
    float v = feat[(size_t)s * 128 + t] * w;
    atomicAdd(&acc[(size_t)d * 128 + t], v);
    if ((t & 31) == 0) atomicAdd(&denom[d * HEADS + h], w);
}

// ---------------------------------------------------------------------------
// Layer-1 finalize: h1[n,f] = elu(acc[n,f] / denom[n,h])
// ---------------------------------------------------------------------------
__global__ __launch_bounds__(256) void finalize_kernel(
    const float* __restrict__ acc, const float* __restrict__ denom,
    float* __restrict__ out, int total)
{
    int i = blockIdx.x * 256 + threadIdx.x;
    if (i >= total) return;
    int n = i >> 7;
    int h = (i >> 5) & 3;
    float den = denom[n * HEADS + h];
    float r = den > 0.f ? acc[i] / den : 0.f;
    out[i] = r > 0.f ? r : expm1f(r);
}

// ---------------------------------------------------------------------------
// Layer-2 finalize + head mean: out[n,d] = mean_h elu(acc[n,h,d]/denom[n,h])
// ---------------------------------------------------------------------------
__global__ __launch_bounds__(256) void final_mean_kernel(
    const float* __restrict__ acc, const float* __restrict__ denom,
    float* __restrict__ out, int nnodes)
{
    int i = blockIdx.x * 256 + threadIdx.x;
    if (i >= nnodes * DD) return;
    int n = i >> 5;
    int d = i & 31;
    float s = 0.f;
    #pragma unroll
    for (int h = 0; h < HEADS; ++h) {
        float den = denom[n * HEADS + h];
        float r = den > 0.f ? acc[(size_t)n * 128 + h * DD + d] / den : 0.f;
        s += r > 0.f ? r : expm1f(r);
    }
    out[i] = 0.25f * s;
}

// ---------------------------------------------------------------------------
extern "C" void kernel_launch(void* const* d_in, const int* in_sizes, int n_in,
                              void* d_out, int out_size, void* d_ws, size_t ws_size,
                              hipStream_t stream)
{
    const float* x   = (const float*)d_in[0];
    const int*   src = (const int*)d_in[1];
    const int*   dst = (const int*)d_in[2];
    const float* W1  = (const float*)d_in[3];
    const float* al1 = (const float*)d_in[4];
    const float* ar1 = (const float*)d_in[5];
    const float* W2  = (const float*)d_in[6];
    const float* al2 = (const float*)d_in[7];
    const float* ar2 = (const float*)d_in[8];
    float* out = (float*)d_out;

    const int N = in_sizes[0] / FDIM;
    const int E = in_sizes[1];

    // workspace layout (floats): A[N*128] | B[N*128] | el[N*4] | er[N*4] | den[N*4]
    float* A  = (float*)d_ws;
    float* B  = A + (size_t)N * FDIM;
    float* el = B + (size_t)N * FDIM;
    float* er = el + (size_t)N * HEADS;
    float* den = er + (size_t)N * HEADS;

    const int gemm_grid = (N + 63) / 64;
    const int edge_grid = (int)(((long long)E * 128 + 255) / 256);
    const int nf = N * FDIM;

    // ---- layer 1 ----
    gemm_elr_kernel<<<gemm_grid, 256, 0, stream>>>(x, W1, al1, ar1, A, el, er, N);
    hipMemsetAsync(B, 0, (size_t)N * FDIM * sizeof(float), stream);
    hipMemsetAsync(den, 0, (size_t)N * HEADS * sizeof(float), stream);
    edge_kernel<<<edge_grid, 256, 0, stream>>>(A, el, er, src, dst, B, den, E);
    finalize_kernel<<<(nf + 255) / 256, 256, 0, stream>>>(B, den, A, nf);

    // ---- layer 2 ----
    gemm_elr_kernel<<<gemm_grid, 256, 0, stream>>>(A, W2, al2, ar2, B, el, er, N);
    hipMemsetAsync(A, 0, (size_t)N * FDIM * sizeof(float), stream);
    hipMemsetAsync(den, 0, (size_t)N * HEADS * sizeof(float), stream);
    edge_kernel<<<edge_grid, 256, 0, stream>>>(B, el, er, src, dst, A, den, E);
    final_mean_kernel<<<(N * DD + 255) / 256, 256, 0, stream>>>(A, den, out, N);
}

// Round 2
// 531.854 us; speedup vs baseline: 2.0948x; 2.0948x over previous
//
#include <hip/hip_runtime.h>
#include <cmath>

#define HEADS 4
#define DD 32
#define FDIM 128   // H*D == IN_DIM == 128
#define NEG 0.2f

// ---------------------------------------------------------------------------
// feat = X @ W^T  (X: [N,128], W: [128,128] row-major, feat: [N,128])
// plus el[n,h] = sum_d feat[n,h,d]*al[h*32+d], er likewise.
// Block: 256 threads, 64 nodes. Per-thread register tile: 4 f x 8 nodes.
// ---------------------------------------------------------------------------
__global__ __launch_bounds__(256) void gemm_elr_kernel(
    const float* __restrict__ X, const float* __restrict__ W,
    const float* __restrict__ al, const float* __restrict__ ar,
    float* __restrict__ feat, float* __restrict__ el, float* __restrict__ er,
    int nnodes)
{
    __shared__ float xsT[128 * 68];   // 34816 B
    const int tid = threadIdx.x;
    const int nb0 = blockIdx.x * 64;

    #pragma unroll
    for (int j = 0; j < 8; ++j) {
        int fidx = tid + j * 256;          // 0..2047 float4 slots
        int n  = fidx >> 5;                // node within block
        int k4 = fidx & 31;                // float4 index along k
        float4 v = make_float4(0.f, 0.f, 0.f, 0.f);
        if (nb0 + n < nnodes)
            v = ((const float4*)X)[(size_t)(nb0 + n) * 32 + k4];
        xsT[(4 * k4 + 0) * 68 + n] = v.x;
        xsT[(4 * k4 + 1) * 68 + n] = v.y;
        xsT[(4 * k4 + 2) * 68 + n] = v.z;
        xsT[(4 * k4 + 3) * 68 + n] = v.w;
    }
    __syncthreads();

    const int fbase = (tid & 31) * 4;      // 4 consecutive output features
    const int nbase = (tid >> 5) * 8;      // 8 consecutive nodes

    float acc[4][8];
    #pragma unroll
    for (int a = 0; a < 4; ++a)
        #pragma unroll
        for (int b = 0; b < 8; ++b) acc[a][b] = 0.f;

    for (int kc = 0; kc < 128; kc += 8) {
        float wreg[4][8];
        #pragma unroll
        for (int ff = 0; ff < 4; ++ff) {
            float4 a = *(const float4*)&W[(fbase + ff) * 128 + kc];
            float4 b = *(const float4*)&W[(fbase + ff) * 128 + kc + 4];
            wreg[ff][0] = a.x; wreg[ff][1] = a.y; wreg[ff][2] = a.z; wreg[ff][3] = a.w;
            wreg[ff][4] = b.x; wreg[ff][5] = b.y; wreg[ff][6] = b.z; wreg[ff][7] = b.w;
        }
        #pragma unroll
        for (int k = 0; k < 8; ++k) {
            float4 x0 = *(const float4*)&xsT[(kc + k) * 68 + nbase];
            float4 x1 = *(const float4*)&xsT[(kc + k) * 68 + nbase + 4];
            float xv[8] = {x0.x, x0.y, x0.z, x0.w, x1.x, x1.y, x1.z, x1.w};
            #pragma unroll
            for (int ff = 0; ff < 4; ++ff)
                #pragma unroll
                for (int nn = 0; nn < 8; ++nn)
                    acc[ff][nn] += wreg[ff][k] * xv[nn];
        }
    }

    #pragma unroll
    for (int nn = 0; nn < 8; ++nn) {
        int gn = nb0 + nbase + nn;
        if (gn < nnodes) {
            float4 v = make_float4(acc[0][nn], acc[1][nn], acc[2][nn], acc[3][nn]);
            *(float4*)&feat[(size_t)gn * 128 + fbase] = v;
        }
    }

    float alv[4], arv[4];
    #pragma unroll
    for (int ff = 0; ff < 4; ++ff) { alv[ff] = al[fbase + ff]; arv[ff] = ar[fbase + ff]; }

    float pel[8], per[8];
    #pragma unroll
    for (int nn = 0; nn < 8; ++nn) {
        float sl = 0.f, sr = 0.f;
        #pragma unroll
        for (int ff = 0; ff < 4; ++ff) {
            sl += acc[ff][nn] * alv[ff];
            sr += acc[ff][nn] * arv[ff];
        }
        pel[nn] = sl; per[nn] = sr;
    }
    #pragma unroll
    for (int off = 4; off >= 1; off >>= 1) {
        #pragma unroll
        for (int nn = 0; nn < 8; ++nn) {
            pel[nn] += __shfl_down(pel[nn], off, 8);
            per[nn] += __shfl_down(per[nn], off, 8);
        }
    }
    if ((tid & 7) == 0) {
        int h = (tid & 31) >> 3;
        #pragma unroll
        for (int nn = 0; nn < 8; ++nn) {
            int gn = nb0 + nbase + nn;
            if (gn < nnodes) {
                el[gn * HEADS + h] = pel[nn];
                er[gn * HEADS + h] = per[nn];
            }
        }
    }
}

// ---------------------------------------------------------------------------
// CSR build: histogram of dst -> exclusive scan -> scatter src ids by dst.
// Built once per launch; shared by both layers.
// ---------------------------------------------------------------------------
__global__ __launch_bounds__(256) void hist_kernel(
    const int* __restrict__ dst, int* __restrict__ counts, int nedges)
{
    int i = blockIdx.x * 256 + threadIdx.x;
    if (i < nedges) atomicAdd(&counts[dst[i]], 1);
}

// single-block two-level (shuffle + LDS) exclusive scan over n counts
__global__ __launch_bounds__(1024) void scan_kernel(
    const int* __restrict__ counts, int* __restrict__ offsets,
    int* __restrict__ cursor, int n)
{
    __shared__ int wsum[16];
    __shared__ int srun;
    const int tid = threadIdx.x;
    const int lane = tid & 63, w = tid >> 6;
    if (tid == 0) srun = 0;
    __syncthreads();
    for (int base = 0; base < n; base += 1024) {
        int i = base + tid;
        int v = (i < n) ? counts[i] : 0;
        int x = v;                          // inclusive wave scan
        #pragma unroll
        for (int off = 1; off < 64; off <<= 1) {
            int t = __shfl_up(x, off, 64);
            if (lane >= off) x += t;
        }
        if (lane == 63) wsum[w] = x;
        __syncthreads();
        if (w == 0 && lane < 16) {          // scan the 16 wave sums
            int s = wsum[lane];
            #pragma unroll
            for (int off = 1; off < 16; off <<= 1) {
                int t = __shfl_up(s, off, 16);
                if ((lane & 15) >= off) s += t;
            }
            wsum[lane] = s;                 // inclusive
        }
        __syncthreads();
        int woff = (w == 0) ? 0 : wsum[w - 1];
        int run = srun;
        int excl = run + woff + x - v;
        if (i < n) { offsets[i] = excl; cursor[i] = excl; }
        __syncthreads();
        if (tid == 1023) srun = run + wsum[15];
        __syncthreads();
    }
    if (tid == 0) offsets[n] = srun;
}

__global__ __launch_bounds__(256) void scatter_kernel(
    const int* __restrict__ src, const int* __restrict__ dst,
    int* __restrict__ cursor, int* __restrict__ csr_src, int nedges)
{
    int i = blockIdx.x * 256 + threadIdx.x;
    if (i < nedges) {
        int pos = atomicAdd(&cursor[dst[i]], 1);
        csr_src[pos] = src[i];
    }
}

// ---------------------------------------------------------------------------
// Gather aggregation: one wave per dst node, 2 features per lane.
// acc = sum_j exp(lrelu(el[s_j]+er[n])) * feat[s_j]; fused /denom + ELU.
// MEAN: also average over heads and write [N,32] output.
// ---------------------------------------------------------------------------
template <bool MEAN>
__global__ __launch_bounds__(256) void aggregate_kernel(
    const float* __restrict__ feat, const float* __restrict__ el,
    const float* __restrict__ er, const int* __restrict__ offsets,
    const int* __restrict__ csr_src, float* __restrict__ out, int nnodes)
{
    int n = (blockIdx.x * 256 + threadIdx.x) >> 6;
    if (n >= nnodes) return;
    const int lane = threadIdx.x & 63;
    const int h = lane >> 4;               // features 2*lane, 2*lane+1 share a head
    const int beg = offsets[n], end = offsets[n + 1];
    const float ern = er[n * HEADS + h];

    float acc0 = 0.f, acc1 = 0.f, sw = 0.f;
    for (int j = beg; j < end; ++j) {
        int s = csr_src[j];
        float e = el[s * HEADS + h] + ern;
        e = e > 0.f ? e : NEG * e;
        float wgt = __expf(e);
        float2 f = ((const float2*)feat)[(size_t)s * 64 + lane];
        acc0 += wgt * f.x;
        acc1 += wgt * f.y;
        sw += wgt;
    }
    float inv = sw > 0.f ? 1.f / sw : 0.f;
    float r0 = acc0 * inv, r1 = acc1 * inv;
    r0 = r0 > 0.f ? r0 : expm1f(r0);
    r1 = r1 > 0.f ? r1 : expm1f(r1);

    if (!MEAN) {
        ((float2*)out)[(size_t)n * 64 + lane] = make_float2(r0, r1);
    } else {
        // sum the 4 head-copies of each d: lanes {q, q+16, q+32, q+48}
        r0 += __shfl_xor(r0, 16, 64);
        r1 += __shfl_xor(r1, 16, 64);
        r0 += __shfl_xor(r0, 32, 64);
        r1 += __shfl_xor(r1, 32, 64);
        if (lane < 16)
            ((float2*)out)[(size_t)n * 16 + lane] = make_float2(0.25f * r0, 0.25f * r1);
    }
}

// ---------------------------------------------------------------------------
extern "C" void kernel_launch(void* const* d_in, const int* in_sizes, int n_in,
                              void* d_out, int out_size, void* d_ws, size_t ws_size,
                              hipStream_t stream)
{
    const float* x   = (const float*)d_in[0];
    const int*   src = (const int*)d_in[1];
    const int*   dst = (const int*)d_in[2];
    const float* W1  = (const float*)d_in[3];
    const float* al1 = (const float*)d_in[4];
    const float* ar1 = (const float*)d_in[5];
    const float* W2  = (const float*)d_in[6];
    const float* al2 = (const float*)d_in[7];
    const float* ar2 = (const float*)d_in[8];
    float* out = (float*)d_out;

    const int N = in_sizes[0] / FDIM;
    const int E = in_sizes[1];

    // workspace: A[N*128] | B[N*128] | el[N*4] | er[N*4] | counts[N] |
    //            offsets[N+1] | cursor[N] | csr_src[E]
    float* A  = (float*)d_ws;
    float* B  = A + (size_t)N * FDIM;
    float* el = B + (size_t)N * FDIM;
    float* er = el + (size_t)N * HEADS;
    int* counts  = (int*)(er + (size_t)N * HEADS);
    int* offsets = counts + N;
    int* cursor  = offsets + (N + 1);
    int* csr_src = cursor + N;

    const int gemm_grid = (N + 63) / 64;
    const int edge_grid = (E + 255) / 256;
    const int agg_grid  = (N * 64 + 255) / 256;

    // ---- CSR build (once; shared by both layers) ----
    hipMemsetAsync(counts, 0, (size_t)N * sizeof(int), stream);
    hist_kernel<<<edge_grid, 256, 0, stream>>>(dst, counts, E);
    scan_kernel<<<1, 1024, 0, stream>>>(counts, offsets, cursor, N);
    scatter_kernel<<<edge_grid, 256, 0, stream>>>(src, dst, cursor, csr_src, E);

    // ---- layer 1 ----
    gemm_elr_kernel<<<gemm_grid, 256, 0, stream>>>(x, W1, al1, ar1, A, el, er, N);
    aggregate_kernel<false><<<agg_grid, 256, 0, stream>>>(A, el, er, offsets, csr_src, B, N);

    // ---- layer 2 ----
    gemm_elr_kernel<<<gemm_grid, 256, 0, stream>>>(B, W2, al2, ar2, A, el, er, N);
    aggregate_kernel<true><<<agg_grid, 256, 0, stream>>>(A, el, er, offsets, csr_src, out, N);
}

// Round 3
// 432.827 us; speedup vs baseline: 2.5741x; 1.2288x over previous
//
#include <hip/hip_runtime.h>
#include <cmath>

#define HEADS 4
#define DD 32
#define FDIM 128   // H*D == IN_DIM == 128
#define NEG 0.2f

// ---------------------------------------------------------------------------
// feat = X @ W^T  (X: [N,128], W: [128,128] row-major, feat: [N,128])
// plus el[n,h] = sum_d feat[n,h,d]*al[h*32+d], er likewise.
// Block: 256 threads, 64 nodes. Per-thread register tile: 4 f x 8 nodes.
// ---------------------------------------------------------------------------
__global__ __launch_bounds__(256) void gemm_elr_kernel(
    const float* __restrict__ X, const float* __restrict__ W,
    const float* __restrict__ al, const float* __restrict__ ar,
    float* __restrict__ feat, float* __restrict__ el, float* __restrict__ er,
    int nnodes)
{
    __shared__ float xsT[128 * 68];   // 34816 B
    const int tid = threadIdx.x;
    const int nb0 = blockIdx.x * 64;

    #pragma unroll
    for (int j = 0; j < 8; ++j) {
        int fidx = tid + j * 256;          // 0..2047 float4 slots
        int n  = fidx >> 5;                // node within block
        int k4 = fidx & 31;                // float4 index along k
        float4 v = make_float4(0.f, 0.f, 0.f, 0.f);
        if (nb0 + n < nnodes)
            v = ((const float4*)X)[(size_t)(nb0 + n) * 32 + k4];
        xsT[(4 * k4 + 0) * 68 + n] = v.x;
        xsT[(4 * k4 + 1) * 68 + n] = v.y;
        xsT[(4 * k4 + 2) * 68 + n] = v.z;
        xsT[(4 * k4 + 3) * 68 + n] = v.w;
    }
    __syncthreads();

    const int fbase = (tid & 31) * 4;      // 4 consecutive output features
    const int nbase = (tid >> 5) * 8;      // 8 consecutive nodes

    float acc[4][8];
    #pragma unroll
    for (int a = 0; a < 4; ++a)
        #pragma unroll
        for (int b = 0; b < 8; ++b) acc[a][b] = 0.f;

    for (int kc = 0; kc < 128; kc += 8) {
        float wreg[4][8];
        #pragma unroll
        for (int ff = 0; ff < 4; ++ff) {
            float4 a = *(const float4*)&W[(fbase + ff) * 128 + kc];
            float4 b = *(const float4*)&W[(fbase + ff) * 128 + kc + 4];
            wreg[ff][0] = a.x; wreg[ff][1] = a.y; wreg[ff][2] = a.z; wreg[ff][3] = a.w;
            wreg[ff][4] = b.x; wreg[ff][5] = b.y; wreg[ff][6] = b.z; wreg[ff][7] = b.w;
        }
        #pragma unroll
        for (int k = 0; k < 8; ++k) {
            float4 x0 = *(const float4*)&xsT[(kc + k) * 68 + nbase];
            float4 x1 = *(const float4*)&xsT[(kc + k) * 68 + nbase + 4];
            float xv[8] = {x0.x, x0.y, x0.z, x0.w, x1.x, x1.y, x1.z, x1.w};
            #pragma unroll
            for (int ff = 0; ff < 4; ++ff)
                #pragma unroll
                for (int nn = 0; nn < 8; ++nn)
                    acc[ff][nn] += wreg[ff][k] * xv[nn];
        }
    }

    #pragma unroll
    for (int nn = 0; nn < 8; ++nn) {
        int gn = nb0 + nbase + nn;
        if (gn < nnodes) {
            float4 v = make_float4(acc[0][nn], acc[1][nn], acc[2][nn], acc[3][nn]);
            *(float4*)&feat[(size_t)gn * 128 + fbase] = v;
        }
    }

    float alv[4], arv[4];
    #pragma unroll
    for (int ff = 0; ff < 4; ++ff) { alv[ff] = al[fbase + ff]; arv[ff] = ar[fbase + ff]; }

    float pel[8], per[8];
    #pragma unroll
    for (int nn = 0; nn < 8; ++nn) {
        float sl = 0.f, sr = 0.f;
        #pragma unroll
        for (int ff = 0; ff < 4; ++ff) {
            sl += acc[ff][nn] * alv[ff];
            sr += acc[ff][nn] * arv[ff];
        }
        pel[nn] = sl; per[nn] = sr;
    }
    #pragma unroll
    for (int off = 4; off >= 1; off >>= 1) {
        #pragma unroll
        for (int nn = 0; nn < 8; ++nn) {
            pel[nn] += __shfl_down(pel[nn], off, 8);
            per[nn] += __shfl_down(per[nn], off, 8);
        }
    }
    if ((tid & 7) == 0) {
        int h = (tid & 31) >> 3;
        #pragma unroll
        for (int nn = 0; nn < 8; ++nn) {
            int gn = nb0 + nbase + nn;
            if (gn < nnodes) {
                el[gn * HEADS + h] = pel[nn];
                er[gn * HEADS + h] = per[nn];
            }
        }
    }
}

// ---------------------------------------------------------------------------
// CSR build: histogram -> 3-kernel hierarchical exclusive scan -> scatter.
// ---------------------------------------------------------------------------
__global__ __launch_bounds__(256) void hist_kernel(
    const int* __restrict__ dst, int* __restrict__ counts, int nedges)
{
    int i = blockIdx.x * 256 + threadIdx.x;
    if (i < nedges) atomicAdd(&counts[dst[i]], 1);
}

// pass 1: each block scans 1024 counts (4/thread); writes block-local
// exclusive offsets + per-block total.
__global__ __launch_bounds__(256) void scan1_kernel(
    const int* __restrict__ counts, int* __restrict__ offsets,
    int* __restrict__ bsums, int n)
{
    __shared__ int wsums[4];
    const int tid = threadIdx.x, lane = tid & 63, w = tid >> 6;
    const int i = blockIdx.x * 1024 + tid * 4;

    int4 v = make_int4(0, 0, 0, 0);
    if (i + 3 < n) v = *(const int4*)&counts[i];
    else {
        if (i < n)     v.x = counts[i];
        if (i + 1 < n) v.y = counts[i + 1];
        if (i + 2 < n) v.z = counts[i + 2];
    }
    int s0 = v.x, s1 = s0 + v.y, s2 = s1 + v.z, s3 = s2 + v.w;

    int x = s3;                              // inclusive wave scan of thread sums
    #pragma unroll
    for (int off = 1; off < 64; off <<= 1) {
        int t = __shfl_up(x, off, 64);
        if (lane >= off) x += t;
    }
    if (lane == 63) wsums[w] = x;
    __syncthreads();
    int wbase = 0;
    #pragma unroll
    for (int k = 0; k < 4; ++k) if (k < w) wbase += wsums[k];

    int tbase = wbase + x - s3;              // exclusive base for this thread
    if (i < n)     offsets[i]     = tbase;
    if (i + 1 < n) offsets[i + 1] = tbase + s0;
    if (i + 2 < n) offsets[i + 2] = tbase + s1;
    if (i + 3 < n) offsets[i + 3] = tbase + s2;
    if (tid == 255) bsums[blockIdx.x] = wbase + x;   // block total
}

// pass 2: single wave, exclusive-scan the block sums in place.
__global__ __launch_bounds__(64) void scan2_kernel(int* __restrict__ bsums, int nb)
{
    const int lane = threadIdx.x;
    int run = 0;
    for (int base = 0; base < nb; base += 64) {
        int i = base + lane;
        int v = (i < nb) ? bsums[i] : 0;
        int x = v;
        #pragma unroll
        for (int off = 1; off < 64; off <<= 1) {
            int t = __shfl_up(x, off, 64);
            if (lane >= off) x += t;
        }
        if (i < nb) bsums[i] = run + x - v;
        run += __shfl(x, 63, 64);
    }
}

// pass 3: add block bases, init cursor, write offsets[n] = E.
__global__ __launch_bounds__(256) void scan3_kernel(
    int* __restrict__ offsets, int* __restrict__ cursor,
    const int* __restrict__ bsums, int n, int nedges)
{
    const int i = blockIdx.x * 1024 + threadIdx.x * 4;
    const int base = bsums[blockIdx.x];
    #pragma unroll
    for (int k = 0; k < 4; ++k) {
        if (i + k < n) {
            int o = offsets[i + k] + base;
            offsets[i + k] = o;
            cursor[i + k] = o;
        }
    }
    if (blockIdx.x == 0 && threadIdx.x == 0) offsets[n] = nedges;
}

__global__ __launch_bounds__(256) void scatter_kernel(
    const int* __restrict__ src, const int* __restrict__ dst,
    int* __restrict__ cursor, int* __restrict__ csr_src, int nedges)
{
    int i = blockIdx.x * 256 + threadIdx.x;
    if (i < nedges) {
        int pos = atomicAdd(&cursor[dst[i]], 1);
        csr_src[pos] = src[i];
    }
}

// ---------------------------------------------------------------------------
// Gather aggregation: one wave per dst node, 2 features per lane.
// Unrolled x4 with batched loads -> 4 concurrent gather chains.
// ---------------------------------------------------------------------------
template <bool MEAN>
__global__ __launch_bounds__(256) void aggregate_kernel(
    const float* __restrict__ feat, const float* __restrict__ el,
    const float* __restrict__ er, const int* __restrict__ offsets,
    const int* __restrict__ csr_src, float* __restrict__ out, int nnodes)
{
    int n = (blockIdx.x * 256 + threadIdx.x) >> 6;
    if (n >= nnodes) return;
    const int lane = threadIdx.x & 63;
    const int h = lane >> 4;
    const int beg = offsets[n], end = offsets[n + 1];
    const float ern = er[n * HEADS + h];
    const float2* __restrict__ feat2 = (const float2*)feat;

    float acc0 = 0.f, acc1 = 0.f, sw = 0.f;
    int j = beg;
    for (; j + 4 <= end; j += 4) {
        int s0 = csr_src[j], s1 = csr_src[j + 1];
        int s2 = csr_src[j + 2], s3 = csr_src[j + 3];
        float e0 = el[s0 * HEADS + h], e1 = el[s1 * HEADS + h];
        float e2 = el[s2 * HEADS + h], e3 = el[s3 * HEADS + h];
        float2 f0 = feat2[(size_t)s0 * 64 + lane];
        float2 f1 = feat2[(size_t)s1 * 64 + lane];
        float2 f2 = feat2[(size_t)s2 * 64 + lane];
        float2 f3 = feat2[(size_t)s3 * 64 + lane];
        e0 += ern; e1 += ern; e2 += ern; e3 += ern;
        e0 = e0 > 0.f ? e0 : NEG * e0;
        e1 = e1 > 0.f ? e1 : NEG * e1;
        e2 = e2 > 0.f ? e2 : NEG * e2;
        e3 = e3 > 0.f ? e3 : NEG * e3;
        float w0 = __expf(e0), w1 = __expf(e1);
        float w2 = __expf(e2), w3 = __expf(e3);
        acc0 += w0 * f0.x + w1 * f1.x + w2 * f2.x + w3 * f3.x;
        acc1 += w0 * f0.y + w1 * f1.y + w2 * f2.y + w3 * f3.y;
        sw   += w0 + w1 + w2 + w3;
    }
    for (; j < end; ++j) {
        int s = csr_src[j];
        float e = el[s * HEADS + h] + ern;
        e = e > 0.f ? e : NEG * e;
        float wgt = __expf(e);
        float2 f = feat2[(size_t)s * 64 + lane];
        acc0 += wgt * f.x;
        acc1 += wgt * f.y;
        sw += wgt;
    }

    float inv = sw > 0.f ? 1.f / sw : 0.f;
    float r0 = acc0 * inv, r1 = acc1 * inv;
    r0 = r0 > 0.f ? r0 : expm1f(r0);
    r1 = r1 > 0.f ? r1 : expm1f(r1);

    if (!MEAN) {
        ((float2*)out)[(size_t)n * 64 + lane] = make_float2(r0, r1);
    } else {
        r0 += __shfl_xor(r0, 16, 64);
        r1 += __shfl_xor(r1, 16, 64);
        r0 += __shfl_xor(r0, 32, 64);
        r1 += __shfl_xor(r1, 32, 64);
        if (lane < 16)
            ((float2*)out)[(size_t)n * 16 + lane] = make_float2(0.25f * r0, 0.25f * r1);
    }
}

// ---------------------------------------------------------------------------
extern "C" void kernel_launch(void* const* d_in, const int* in_sizes, int n_in,
                              void* d_out, int out_size, void* d_ws, size_t ws_size,
                              hipStream_t stream)
{
    const float* x   = (const float*)d_in[0];
    const int*   src = (const int*)d_in[1];
    const int*   dst = (const int*)d_in[2];
    const float* W1  = (const float*)d_in[3];
    const float* al1 = (const float*)d_in[4];
    const float* ar1 = (const float*)d_in[5];
    const float* W2  = (const float*)d_in[6];
    const float* al2 = (const float*)d_in[7];
    const float* ar2 = (const float*)d_in[8];
    float* out = (float*)d_out;

    const int N = in_sizes[0] / FDIM;
    const int E = in_sizes[1];

    // workspace: A[N*128] | B[N*128] | el[N*4] | er[N*4] | counts[N] |
    //            offsets[N+1] | cursor[N] | csr_src[E] | bsums[..]
    float* A  = (float*)d_ws;
    float* B  = A + (size_t)N * FDIM;
    float* el = B + (size_t)N * FDIM;
    float* er = el + (size_t)N * HEADS;
    int* counts  = (int*)(er + (size_t)N * HEADS);
    int* offsets = counts + N;
    int* cursor  = offsets + (N + 1);
    int* csr_src = cursor + N;
    int* bsums   = csr_src + E;

    const int gemm_grid = (N + 63) / 64;
    const int edge_grid = (E + 255) / 256;
    const int agg_grid  = (N * 64 + 255) / 256;
    const int nscan     = (N + 1023) / 1024;

    // ---- CSR build (once; shared by both layers) ----
    hipMemsetAsync(counts, 0, (size_t)N * sizeof(int), stream);
    hist_kernel<<<edge_grid, 256, 0, stream>>>(dst, counts, E);
    scan1_kernel<<<nscan, 256, 0, stream>>>(counts, offsets, bsums, N);
    scan2_kernel<<<1, 64, 0, stream>>>(bsums, nscan);
    scan3_kernel<<<nscan, 256, 0, stream>>>(offsets, cursor, bsums, N, E);
    scatter_kernel<<<edge_grid, 256, 0, stream>>>(src, dst, cursor, csr_src, E);

    // ---- layer 1 ----
    gemm_elr_kernel<<<gemm_grid, 256, 0, stream>>>(x, W1, al1, ar1, A, el, er, N);
    aggregate_kernel<false><<<agg_grid, 256, 0, stream>>>(A, el, er, offsets, csr_src, B, N);

    // ---- layer 2 ----
    gemm_elr_kernel<<<gemm_grid, 256, 0, stream>>>(B, W2, al2, ar2, A, el, er, N);
    aggregate_kernel<true><<<agg_grid, 256, 0, stream>>>(A, el, er, offsets, csr_src, out, N);
}

// Round 4
// 378.513 us; speedup vs baseline: 2.9435x; 1.1435x over previous
//
#include <hip/hip_runtime.h>
#include <cmath>

#define HEADS 4
#define DD 32
#define FDIM 128   // H*D == IN_DIM == 128
#define NEG 0.2f

typedef __attribute__((ext_vector_type(8))) __bf16 bf16x8;
typedef __attribute__((ext_vector_type(4))) float f32x4;

// ---------------------------------------------------------------------------
// Split W (f32 [128][128], row-major by out-feature) into bf16 hi/lo halves.
// ---------------------------------------------------------------------------
__global__ __launch_bounds__(256) void wconv_kernel(
    const float* __restrict__ W, __bf16* __restrict__ whi, __bf16* __restrict__ wlo)
{
    int i = blockIdx.x * 256 + threadIdx.x;   // 16384 total
    float w = W[i];
    __bf16 h = (__bf16)w;
    whi[i] = h;
    wlo[i] = (__bf16)(w - (float)h);
}

// ---------------------------------------------------------------------------
// MFMA GEMM: feat[n][f] = sum_k X[n][k] * W[f][k], split-bf16 (hi*hi + lo*hi
// + hi*lo), fused el/er epilogue. 4 waves/block, 16 nodes/wave, no LDS.
// Layouts (m89/m91/m120-verified): A[m=lane&15][k=quad*8+j],
// B[k=quad*8+j][n=lane&15], D[row=quad*4+reg][col=lane&15].
// ---------------------------------------------------------------------------
__global__ __launch_bounds__(256) void gemm_mfma_kernel(
    const float* __restrict__ X,
    const __bf16* __restrict__ whi, const __bf16* __restrict__ wlo,
    const float* __restrict__ al, const float* __restrict__ ar,
    float* __restrict__ feat, float* __restrict__ el, float* __restrict__ er,
    int nnodes)
{
    const int tid  = threadIdx.x;
    const int wave = tid >> 6, lane = tid & 63;
    const int l15  = lane & 15, quad = lane >> 4;
    const int nb   = blockIdx.x * 64 + wave * 16;
    const int nodeA = nb + l15;          // m-row this lane feeds into A
    const bool validA = nodeA < nnodes;
    const int nodeC = nb + quad * 4;     // +r = node this lane's C regs hold

    f32x4 acc[8];
    #pragma unroll
    for (int t = 0; t < 8; ++t) acc[t] = (f32x4){0.f, 0.f, 0.f, 0.f};

    const bf16x8* __restrict__ whv = (const bf16x8*)whi;  // [f][16] frags
    const bf16x8* __restrict__ wlv = (const bf16x8*)wlo;

    #pragma unroll
    for (int ks = 0; ks < 4; ++ks) {
        // A fragment: X[nodeA][ks*32 + quad*8 .. +8)
        float xa[8];
        if (validA) {
            float4 x0 = *(const float4*)&X[(size_t)nodeA * 128 + ks * 32 + quad * 8];
            float4 x1 = *(const float4*)&X[(size_t)nodeA * 128 + ks * 32 + quad * 8 + 4];
            xa[0] = x0.x; xa[1] = x0.y; xa[2] = x0.z; xa[3] = x0.w;
            xa[4] = x1.x; xa[5] = x1.y; xa[6] = x1.z; xa[7] = x1.w;
        } else {
            #pragma unroll
            for (int j = 0; j < 8; ++j) xa[j] = 0.f;
        }
        bf16x8 ahi, alo;
        #pragma unroll
        for (int j = 0; j < 8; ++j) {
            __bf16 h = (__bf16)xa[j];
            ahi[j] = h;
            alo[j] = (__bf16)(xa[j] - (float)h);
        }

        #pragma unroll
        for (int t = 0; t < 8; ++t) {
            int f = t * 16 + l15;
            bf16x8 bh = whv[f * 16 + ks * 4 + quad];
            bf16x8 bl = wlv[f * 16 + ks * 4 + quad];
            acc[t] = __builtin_amdgcn_mfma_f32_16x16x32_bf16(ahi, bh, acc[t], 0, 0, 0);
            acc[t] = __builtin_amdgcn_mfma_f32_16x16x32_bf16(alo, bh, acc[t], 0, 0, 0);
            acc[t] = __builtin_amdgcn_mfma_f32_16x16x32_bf16(ahi, bl, acc[t], 0, 0, 0);
        }
    }

    // ---- write feat: acc[t][r] -> feat[nodeC+r][t*16 + l15] ----
    #pragma unroll
    for (int r = 0; r < 4; ++r) {
        int gn = nodeC + r;
        if (gn < nnodes) {
            #pragma unroll
            for (int t = 0; t < 8; ++t)
                feat[(size_t)gn * 128 + t * 16 + l15] = acc[t][r];
        }
    }

    // ---- fused el/er: head h spans f-tiles 2h (d=l15) and 2h+1 (d=16+l15) ----
    float pl[4][4], pr[4][4];
    #pragma unroll
    for (int h = 0; h < 4; ++h) {
        float a0 = al[h * 32 + l15], a1 = al[h * 32 + 16 + l15];
        float b0 = ar[h * 32 + l15], b1 = ar[h * 32 + 16 + l15];
        #pragma unroll
        for (int r = 0; r < 4; ++r) {
            pl[h][r] = a0 * acc[2 * h][r] + a1 * acc[2 * h + 1][r];
            pr[h][r] = b0 * acc[2 * h][r] + b1 * acc[2 * h + 1][r];
        }
    }
    #pragma unroll
    for (int off = 1; off < 16; off <<= 1) {
        #pragma unroll
        for (int h = 0; h < 4; ++h)
            #pragma unroll
            for (int r = 0; r < 4; ++r) {
                pl[h][r] += __shfl_xor(pl[h][r], off, 64);
                pr[h][r] += __shfl_xor(pr[h][r], off, 64);
            }
    }
    if (l15 < 4) {
        int h = l15;
        #pragma unroll
        for (int r = 0; r < 4; ++r) {
            int gn = nodeC + r;
            if (gn < nnodes) {
                el[gn * HEADS + h] = pl[h][r];
                er[gn * HEADS + h] = pr[h][r];
            }
        }
    }
}

// ---------------------------------------------------------------------------
// CSR build: histogram -> 3-kernel hierarchical exclusive scan -> scatter.
// ---------------------------------------------------------------------------
__global__ __launch_bounds__(256) void hist_kernel(
    const int* __restrict__ dst, int* __restrict__ counts, int nedges)
{
    int i = blockIdx.x * 256 + threadIdx.x;
    if (i < nedges) atomicAdd(&counts[dst[i]], 1);
}

__global__ __launch_bounds__(256) void scan1_kernel(
    const int* __restrict__ counts, int* __restrict__ offsets,
    int* __restrict__ bsums, int n)
{
    __shared__ int wsums[4];
    const int tid = threadIdx.x, lane = tid & 63, w = tid >> 6;
    const int i = blockIdx.x * 1024 + tid * 4;

    int4 v = make_int4(0, 0, 0, 0);
    if (i + 3 < n) v = *(const int4*)&counts[i];
    else {
        if (i < n)     v.x = counts[i];
        if (i + 1 < n) v.y = counts[i + 1];
        if (i + 2 < n) v.z = counts[i + 2];
    }
    int s0 = v.x, s1 = s0 + v.y, s2 = s1 + v.z, s3 = s2 + v.w;

    int x = s3;
    #pragma unroll
    for (int off = 1; off < 64; off <<= 1) {
        int t = __shfl_up(x, off, 64);
        if (lane >= off) x += t;
    }
    if (lane == 63) wsums[w] = x;
    __syncthreads();
    int wbase = 0;
    #pragma unroll
    for (int k = 0; k < 4; ++k) if (k < w) wbase += wsums[k];

    int tbase = wbase + x - s3;
    if (i < n)     offsets[i]     = tbase;
    if (i + 1 < n) offsets[i + 1] = tbase + s0;
    if (i + 2 < n) offsets[i + 2] = tbase + s1;
    if (i + 3 < n) offsets[i + 3] = tbase + s2;
    if (tid == 255) bsums[blockIdx.x] = wbase + x;
}

__global__ __launch_bounds__(64) void scan2_kernel(int* __restrict__ bsums, int nb)
{
    const int lane = threadIdx.x;
    int run = 0;
    for (int base = 0; base < nb; base += 64) {
        int i = base + lane;
        int v = (i < nb) ? bsums[i] : 0;
        int x = v;
        #pragma unroll
        for (int off = 1; off < 64; off <<= 1) {
            int t = __shfl_up(x, off, 64);
            if (lane >= off) x += t;
        }
        if (i < nb) bsums[i] = run + x - v;
        run += __shfl(x, 63, 64);
    }
}

__global__ __launch_bounds__(256) void scan3_kernel(
    int* __restrict__ offsets, int* __restrict__ cursor,
    const int* __restrict__ bsums, int n, int nedges)
{
    const int i = blockIdx.x * 1024 + threadIdx.x * 4;
    const int base = bsums[blockIdx.x];
    #pragma unroll
    for (int k = 0; k < 4; ++k) {
        if (i + k < n) {
            int o = offsets[i + k] + base;
            offsets[i + k] = o;
            cursor[i + k] = o;
        }
    }
    if (blockIdx.x == 0 && threadIdx.x == 0) offsets[n] = nedges;
}

__global__ __launch_bounds__(256) void scatter_kernel(
    const int* __restrict__ src, const int* __restrict__ dst,
    int* __restrict__ cursor, int* __restrict__ csr_src, int nedges)
{
    int i = blockIdx.x * 256 + threadIdx.x;
    if (i < nedges) {
        int pos = atomicAdd(&cursor[dst[i]], 1);
        csr_src[pos] = src[i];
    }
}

// ---------------------------------------------------------------------------
// Gather aggregation: one wave per dst node, 2 features per lane, unroll x4.
// ---------------------------------------------------------------------------
template <bool MEAN>
__global__ __launch_bounds__(256) void aggregate_kernel(
    const float* __restrict__ feat, const float* __restrict__ el,
    const float* __restrict__ er, const int* __restrict__ offsets,
    const int* __restrict__ csr_src, float* __restrict__ out, int nnodes)
{
    int n = (blockIdx.x * 256 + threadIdx.x) >> 6;
    if (n >= nnodes) return;
    const int lane = threadIdx.x & 63;
    const int h = lane >> 4;
    const int beg = offsets[n], end = offsets[n + 1];
    const float ern = er[n * HEADS + h];
    const float2* __restrict__ feat2 = (const float2*)feat;

    float acc0 = 0.f, acc1 = 0.f, sw = 0.f;
    int j = beg;
    for (; j + 4 <= end; j += 4) {
        int s0 = csr_src[j], s1 = csr_src[j + 1];
        int s2 = csr_src[j + 2], s3 = csr_src[j + 3];
        float e0 = el[s0 * HEADS + h], e1 = el[s1 * HEADS + h];
        float e2 = el[s2 * HEADS + h], e3 = el[s3 * HEADS + h];
        float2 f0 = feat2[(size_t)s0 * 64 + lane];
        float2 f1 = feat2[(size_t)s1 * 64 + lane];
        float2 f2 = feat2[(size_t)s2 * 64 + lane];
        float2 f3 = feat2[(size_t)s3 * 64 + lane];
        e0 += ern; e1 += ern; e2 += ern; e3 += ern;
        e0 = e0 > 0.f ? e0 : NEG * e0;
        e1 = e1 > 0.f ? e1 : NEG * e1;
        e2 = e2 > 0.f ? e2 : NEG * e2;
        e3 = e3 > 0.f ? e3 : NEG * e3;
        float w0 = __expf(e0), w1 = __expf(e1);
        float w2 = __expf(e2), w3 = __expf(e3);
        acc0 += w0 * f0.x + w1 * f1.x + w2 * f2.x + w3 * f3.x;
        acc1 += w0 * f0.y + w1 * f1.y + w2 * f2.y + w3 * f3.y;
        sw   += w0 + w1 + w2 + w3;
    }
    for (; j < end; ++j) {
        int s = csr_src[j];
        float e = el[s * HEADS + h] + ern;
        e = e > 0.f ? e : NEG * e;
        float wgt = __expf(e);
        float2 f = feat2[(size_t)s * 64 + lane];
        acc0 += wgt * f.x;
        acc1 += wgt * f.y;
        sw += wgt;
    }

    float inv = sw > 0.f ? 1.f / sw : 0.f;
    float r0 = acc0 * inv, r1 = acc1 * inv;
    r0 = r0 > 0.f ? r0 : expm1f(r0);
    r1 = r1 > 0.f ? r1 : expm1f(r1);

    if (!MEAN) {
        ((float2*)out)[(size_t)n * 64 + lane] = make_float2(r0, r1);
    } else {
        r0 += __shfl_xor(r0, 16, 64);
        r1 += __shfl_xor(r1, 16, 64);
        r0 += __shfl_xor(r0, 32, 64);
        r1 += __shfl_xor(r1, 32, 64);
        if (lane < 16)
            ((float2*)out)[(size_t)n * 16 + lane] = make_float2(0.25f * r0, 0.25f * r1);
    }
}

// ---------------------------------------------------------------------------
extern "C" void kernel_launch(void* const* d_in, const int* in_sizes, int n_in,
                              void* d_out, int out_size, void* d_ws, size_t ws_size,
                              hipStream_t stream)
{
    const float* x   = (const float*)d_in[0];
    const int*   src = (const int*)d_in[1];
    const int*   dst = (const int*)d_in[2];
    const float* W1  = (const float*)d_in[3];
    const float* al1 = (const float*)d_in[4];
    const float* ar1 = (const float*)d_in[5];
    const float* W2  = (const float*)d_in[6];
    const float* al2 = (const float*)d_in[7];
    const float* ar2 = (const float*)d_in[8];
    float* out = (float*)d_out;

    const int N = in_sizes[0] / FDIM;
    const int E = in_sizes[1];

    // workspace: A[N*128] | B[N*128] | el[N*4] | er[N*4] | counts[N] |
    //            offsets[N+1] | cursor[N] | csr_src[E] | bsums[256] | W-splits
    float* A  = (float*)d_ws;
    float* B  = A + (size_t)N * FDIM;
    float* el = B + (size_t)N * FDIM;
    float* er = el + (size_t)N * HEADS;
    int* counts  = (int*)(er + (size_t)N * HEADS);
    int* offsets = counts + N;
    int* cursor  = offsets + (N + 1);
    int* csr_src = cursor + N;
    int* bsums   = csr_src + E;
    uintptr_t wp = ((uintptr_t)(bsums + 256) + 63) & ~(uintptr_t)63;
    __bf16* whi1 = (__bf16*)wp;
    __bf16* wlo1 = whi1 + FDIM * FDIM;
    __bf16* whi2 = wlo1 + FDIM * FDIM;
    __bf16* wlo2 = whi2 + FDIM * FDIM;

    const int gemm_grid = (N + 63) / 64;
    const int edge_grid = (E + 255) / 256;
    const int agg_grid  = (N * 64 + 255) / 256;
    const int nscan     = (N + 1023) / 1024;

    // ---- W split (once) + CSR build (once) ----
    wconv_kernel<<<FDIM * FDIM / 256, 256, 0, stream>>>(W1, whi1, wlo1);
    wconv_kernel<<<FDIM * FDIM / 256, 256, 0, stream>>>(W2, whi2, wlo2);
    hipMemsetAsync(counts, 0, (size_t)N * sizeof(int), stream);
    hist_kernel<<<edge_grid, 256, 0, stream>>>(dst, counts, E);
    scan1_kernel<<<nscan, 256, 0, stream>>>(counts, offsets, bsums, N);
    scan2_kernel<<<1, 64, 0, stream>>>(bsums, nscan);
    scan3_kernel<<<nscan, 256, 0, stream>>>(offsets, cursor, bsums, N, E);
    scatter_kernel<<<edge_grid, 256, 0, stream>>>(src, dst, cursor, csr_src, E);

    // ---- layer 1 ----
    gemm_mfma_kernel<<<gemm_grid, 256, 0, stream>>>(x, whi1, wlo1, al1, ar1, A, el, er, N);
    aggregate_kernel<false><<<agg_grid, 256, 0, stream>>>(A, el, er, offsets, csr_src, B, N);

    // ---- layer 2 ----
    gemm_mfma_kernel<<<gemm_grid, 256, 0, stream>>>(B, whi2, wlo2, al2, ar2, A, el, er, N);
    aggregate_kernel<true><<<agg_grid, 256, 0, stream>>>(A, el, er, offsets, csr_src, out, N);
}

// Round 5
// 361.085 us; speedup vs baseline: 3.0855x; 1.0483x over previous
//
#include <hip/hip_runtime.h>
#include <cmath>

#define HEADS 4
#define FDIM 128   // H*D == IN_DIM == 128
#define NEG 0.2f

typedef __attribute__((ext_vector_type(8))) __bf16 bf16x8;
typedef __attribute__((ext_vector_type(4))) float f32x4;

// ---------------------------------------------------------------------------
// val[c][k], c=0..3: sum_d al[c,d]*W[c*32+d][k]; c=4..7: same with ar.
// el[n,h] = X[n,:] . val[h,:]  (so el/er become 8 extra GEMM columns)
// ---------------------------------------------------------------------------
__global__ __launch_bounds__(512) void valcomp_kernel(
    const float* __restrict__ W, const float* __restrict__ al,
    const float* __restrict__ ar, float* __restrict__ val)
{
    int tid = threadIdx.x;            // 512 = 4 heads x 128 k
    int h = tid >> 7, k = tid & 127;
    float sl = 0.f, sr = 0.f;
    for (int d = 0; d < 32; ++d) {
        float w = W[(h * 32 + d) * 128 + k];
        sl += al[h * 32 + d] * w;
        sr += ar[h * 32 + d] * w;
    }
    val[h * 128 + k]       = sl;
    val[512 + h * 128 + k] = sr;
}

// ---------------------------------------------------------------------------
// Build frag-ordered split-bf16 W image (8 tiles of 16 cols):
// wf[((hl*16+kq)*8 + t)*16 + c][j] = hi/lo of W[(t*16+c)*128 + kq*8 + j]
// 32768 bf16 elements.
// ---------------------------------------------------------------------------
__global__ __launch_bounds__(256) void wfrag_kernel(
    const float* __restrict__ W, __bf16* __restrict__ wf)
{
    int idx = blockIdx.x * 256 + threadIdx.x;   // < 32768
    int j = idx & 7;
    int r = idx >> 3;
    int c = r & 15; r >>= 4;
    int t = r & 7;  r >>= 3;
    int kq = r & 15;
    int hl = r >> 4;
    float v = W[(t * 16 + c) * 128 + kq * 8 + j];
    __bf16 hi = (__bf16)v;
    wf[idx] = (hl == 0) ? hi : (__bf16)(v - (float)hi);
}

// el/er tile: wext[(hl*16+kq)*16 + c][j] = hi/lo of val[c*128 + kq*8+j] (c<8)
__global__ __launch_bounds__(256) void wext_kernel(
    const float* __restrict__ val, __bf16* __restrict__ wext)
{
    int idx = blockIdx.x * 256 + threadIdx.x;   // < 4096
    int j = idx & 7;
    int r = idx >> 3;
    int c = r & 15; r >>= 4;
    int kq = r & 15;
    int hl = r >> 4;
    float v = (c < 8) ? val[c * 128 + kq * 8 + j] : 0.f;
    __bf16 hi = (__bf16)v;
    wext[idx] = (hl == 0) ? hi : (__bf16)(v - (float)hi);
}

// ---------------------------------------------------------------------------
// MFMA GEMM, LDS-staged W (64 KB), grid-stride tiles, X reg-prefetch.
// A[m=lane&15][k=quad*8+j], B[k=quad*8+j][n=lane&15], D[row=quad*4+r][col=lane&15].
// acc[0..7] = feat cols, acc[8] = el (cols 0-3) / er (cols 4-7).
// ---------------------------------------------------------------------------
__global__ __launch_bounds__(256) void gemm_mfma_kernel(
    const float* __restrict__ X, const bf16x8* __restrict__ wf,
    const bf16x8* __restrict__ wext,
    float* __restrict__ feat, float* __restrict__ el, float* __restrict__ er,
    int nnodes, int ntiles)
{
    __shared__ bf16x8 lw[4096];   // 65536 B
    const int tid = threadIdx.x;
    for (int i = tid; i < 4096; i += 256) lw[i] = wf[i];
    __syncthreads();

    const int wave = tid >> 6, lane = tid & 63;
    const int l15 = lane & 15, quad = lane >> 4;

    int tile = blockIdx.x;
    float4 xr[8], xn[8];

    auto loadX = [&](int tl, float4* dst) {
        int nodeA = tl * 64 + wave * 16 + l15;
        bool v = nodeA < nnodes;
        const float4* xp = (const float4*)(X + (size_t)nodeA * 128);
        #pragma unroll
        for (int ks = 0; ks < 4; ++ks) {
            dst[2 * ks]     = v ? xp[ks * 8 + quad * 2]     : make_float4(0.f, 0.f, 0.f, 0.f);
            dst[2 * ks + 1] = v ? xp[ks * 8 + quad * 2 + 1] : make_float4(0.f, 0.f, 0.f, 0.f);
        }
    };

    loadX(tile, xr);
    while (true) {
        int next = tile + gridDim.x;
        if (next < ntiles) loadX(next, xn);

        f32x4 acc[9];
        #pragma unroll
        for (int t = 0; t < 9; ++t) acc[t] = (f32x4){0.f, 0.f, 0.f, 0.f};

        #pragma unroll
        for (int ks = 0; ks < 4; ++ks) {
            float xa[8] = {xr[2 * ks].x, xr[2 * ks].y, xr[2 * ks].z, xr[2 * ks].w,
                           xr[2 * ks + 1].x, xr[2 * ks + 1].y, xr[2 * ks + 1].z, xr[2 * ks + 1].w};
            bf16x8 ahi, alo;
            #pragma unroll
            for (int j = 0; j < 8; ++j) {
                __bf16 h = (__bf16)xa[j];
                ahi[j] = h;
                alo[j] = (__bf16)(xa[j] - (float)h);
            }
            const int kq = ks * 4 + quad;

            // el/er tile (global, 8 KB, L1-resident)
            {
                bf16x8 bh = wext[(kq) * 16 + l15];
                bf16x8 bl = wext[(16 + kq) * 16 + l15];
                acc[8] = __builtin_amdgcn_mfma_f32_16x16x32_bf16(ahi, bh, acc[8], 0, 0, 0);
                acc[8] = __builtin_amdgcn_mfma_f32_16x16x32_bf16(alo, bh, acc[8], 0, 0, 0);
                acc[8] = __builtin_amdgcn_mfma_f32_16x16x32_bf16(ahi, bl, acc[8], 0, 0, 0);
            }
            #pragma unroll
            for (int t = 0; t < 8; ++t) {
                bf16x8 bh = lw[(kq * 8 + t) * 16 + l15];
                bf16x8 bl = lw[((16 + kq) * 8 + t) * 16 + l15];
                acc[t] = __builtin_amdgcn_mfma_f32_16x16x32_bf16(ahi, bh, acc[t], 0, 0, 0);
                acc[t] = __builtin_amdgcn_mfma_f32_16x16x32_bf16(alo, bh, acc[t], 0, 0, 0);
                acc[t] = __builtin_amdgcn_mfma_f32_16x16x32_bf16(ahi, bl, acc[t], 0, 0, 0);
            }
        }

        const int nodeC = tile * 64 + wave * 16 + quad * 4;
        #pragma unroll
        for (int r = 0; r < 4; ++r) {
            int gn = nodeC + r;
            if (gn < nnodes) {
                #pragma unroll
                for (int t = 0; t < 8; ++t)
                    feat[(size_t)gn * 128 + t * 16 + l15] = acc[t][r];
            }
        }
        if (l15 < 8) {
            #pragma unroll
            for (int r = 0; r < 4; ++r) {
                int gn = nodeC + r;
                if (gn < nnodes) {
                    if (l15 < 4) el[gn * HEADS + l15] = acc[8][r];
                    else         er[gn * HEADS + (l15 - 4)] = acc[8][r];
                }
            }
        }

        if (next >= ntiles) break;
        #pragma unroll
        for (int i = 0; i < 8; ++i) xr[i] = xn[i];
        tile = next;
    }
}

// ---------------------------------------------------------------------------
// CSR build: histogram -> 3-kernel hierarchical exclusive scan -> scatter.
// ---------------------------------------------------------------------------
__global__ __launch_bounds__(256) void hist_kernel(
    const int* __restrict__ dst, int* __restrict__ counts, int nedges)
{
    int i = blockIdx.x * 256 + threadIdx.x;
    if (i < nedges) atomicAdd(&counts[dst[i]], 1);
}

__global__ __launch_bounds__(256) void scan1_kernel(
    const int* __restrict__ counts, int* __restrict__ offsets,
    int* __restrict__ bsums, int n)
{
    __shared__ int wsums[4];
    const int tid = threadIdx.x, lane = tid & 63, w = tid >> 6;
    const int i = blockIdx.x * 1024 + tid * 4;

    int4 v = make_int4(0, 0, 0, 0);
    if (i + 3 < n) v = *(const int4*)&counts[i];
    else {
        if (i < n)     v.x = counts[i];
        if (i + 1 < n) v.y = counts[i + 1];
        if (i + 2 < n) v.z = counts[i + 2];
    }
    int s0 = v.x, s1 = s0 + v.y, s2 = s1 + v.z, s3 = s2 + v.w;

    int x = s3;
    #pragma unroll
    for (int off = 1; off < 64; off <<= 1) {
        int t = __shfl_up(x, off, 64);
        if (lane >= off) x += t;
    }
    if (lane == 63) wsums[w] = x;
    __syncthreads();
    int wbase = 0;
    #pragma unroll
    for (int k = 0; k < 4; ++k) if (k < w) wbase += wsums[k];

    int tbase = wbase + x - s3;
    if (i < n)     offsets[i]     = tbase;
    if (i + 1 < n) offsets[i + 1] = tbase + s0;
    if (i + 2 < n) offsets[i + 2] = tbase + s1;
    if (i + 3 < n) offsets[i + 3] = tbase + s2;
    if (tid == 255) bsums[blockIdx.x] = wbase + x;
}

__global__ __launch_bounds__(64) void scan2_kernel(int* __restrict__ bsums, int nb)
{
    const int lane = threadIdx.x;
    int run = 0;
    for (int base = 0; base < nb; base += 64) {
        int i = base + lane;
        int v = (i < nb) ? bsums[i] : 0;
        int x = v;
        #pragma unroll
        for (int off = 1; off < 64; off <<= 1) {
            int t = __shfl_up(x, off, 64);
            if (lane >= off) x += t;
        }
        if (i < nb) bsums[i] = run + x - v;
        run += __shfl(x, 63, 64);
    }
}

__global__ __launch_bounds__(256) void scan3_kernel(
    int* __restrict__ offsets, int* __restrict__ cursor,
    const int* __restrict__ bsums, int n, int nedges)
{
    const int i = blockIdx.x * 1024 + threadIdx.x * 4;
    const int base = bsums[blockIdx.x];
    #pragma unroll
    for (int k = 0; k < 4; ++k) {
        if (i + k < n) {
            int o = offsets[i + k] + base;
            offsets[i + k] = o;
            cursor[i + k] = o;
        }
    }
    if (blockIdx.x == 0 && threadIdx.x == 0) offsets[n] = nedges;
}

__global__ __launch_bounds__(256) void scatter_kernel(
    const int* __restrict__ src, const int* __restrict__ dst,
    int* __restrict__ cursor, int* __restrict__ csr_src, int nedges)
{
    int i = blockIdx.x * 256 + threadIdx.x;
    if (i < nedges) {
        int pos = atomicAdd(&cursor[dst[i]], 1);
        csr_src[pos] = src[i];
    }
}

// ---------------------------------------------------------------------------
// Gather aggregation: 4 dst nodes per wave, 16 lanes/node, 8 floats/lane.
// Loop to max degree of the 4 nodes with predication; depth-1 SW pipeline.
// ---------------------------------------------------------------------------
template <bool MEAN>
__global__ __launch_bounds__(256) void aggregate_kernel(
    const float* __restrict__ feat, const float* __restrict__ el,
    const float* __restrict__ er, const int* __restrict__ offsets,
    const int* __restrict__ csr_src, float* __restrict__ out, int nnodes)
{
    const int wid = (blockIdx.x * 256 + threadIdx.x) >> 6;
    const int lane = threadIdx.x & 63;
    const int g = lane >> 4, u = lane & 15, h = u >> 2;
    const int n = wid * 4 + g;
    const bool nv = n < nnodes;

    int beg = 0, end = 0;
    float ern = 0.f;
    if (nv) {
        beg = offsets[n];
        end = offsets[n + 1];
        ern = er[n * HEADS + h];
    }
    int md = end - beg;
    md = max(md, __shfl_xor(md, 16, 64));
    md = max(md, __shfl_xor(md, 32, 64));

    const float4* __restrict__ f4 = (const float4*)feat;

    float4 a0 = make_float4(0.f, 0.f, 0.f, 0.f);
    float4 a1 = make_float4(0.f, 0.f, 0.f, 0.f);
    float sw = 0.f;

    int j = beg;
    bool v = j < end;
    int s = v ? csr_src[j] : 0;
    float q = el[s * HEADS + h];
    float4 f0 = f4[(size_t)s * 32 + u * 2];
    float4 f1 = f4[(size_t)s * 32 + u * 2 + 1];

    for (int it = 0; it < md; ++it) {
        int jn = j + 1;
        bool vn = jn < end;
        int sn = vn ? csr_src[jn] : 0;
        float qn = el[sn * HEADS + h];
        float4 g0 = f4[(size_t)sn * 32 + u * 2];
        float4 g1 = f4[(size_t)sn * 32 + u * 2 + 1];

        float e = q + ern;
        e = e > 0.f ? e : NEG * e;
        float w = v ? __expf(e) : 0.f;
        a0.x += w * f0.x; a0.y += w * f0.y; a0.z += w * f0.z; a0.w += w * f0.w;
        a1.x += w * f1.x; a1.y += w * f1.y; a1.z += w * f1.z; a1.w += w * f1.w;
        sw += w;

        j = jn; v = vn; q = qn; f0 = g0; f1 = g1;
    }

    float inv = sw > 0.f ? 1.f / sw : 0.f;
    float r[8] = {a0.x * inv, a0.y * inv, a0.z * inv, a0.w * inv,
                  a1.x * inv, a1.y * inv, a1.z * inv, a1.w * inv};
    #pragma unroll
    for (int p = 0; p < 8; ++p) r[p] = r[p] > 0.f ? r[p] : expm1f(r[p]);

    if (!MEAN) {
        if (nv) {
            float4* o4 = (float4*)out;
            o4[(size_t)n * 32 + u * 2]     = make_float4(r[0], r[1], r[2], r[3]);
            o4[(size_t)n * 32 + u * 2 + 1] = make_float4(r[4], r[5], r[6], r[7]);
        }
    } else {
        #pragma unroll
        for (int p = 0; p < 8; ++p) {
            r[p] += __shfl_xor(r[p], 4, 64);
            r[p] += __shfl_xor(r[p], 8, 64);
        }
        if (nv && u < 4) {
            float4* o4 = (float4*)out;
            o4[(size_t)n * 8 + u * 2]     = make_float4(0.25f * r[0], 0.25f * r[1],
                                                        0.25f * r[2], 0.25f * r[3]);
            o4[(size_t)n * 8 + u * 2 + 1] = make_float4(0.25f * r[4], 0.25f * r[5],
                                                        0.25f * r[6], 0.25f * r[7]);
        }
    }
}

// ---------------------------------------------------------------------------
extern "C" void kernel_launch(void* const* d_in, const int* in_sizes, int n_in,
                              void* d_out, int out_size, void* d_ws, size_t ws_size,
                              hipStream_t stream)
{
    const float* x   = (const float*)d_in[0];
    const int*   src = (const int*)d_in[1];
    const int*   dst = (const int*)d_in[2];
    const float* W1  = (const float*)d_in[3];
    const float* al1 = (const float*)d_in[4];
    const float* ar1 = (const float*)d_in[5];
    const float* W2  = (const float*)d_in[6];
    const float* al2 = (const float*)d_in[7];
    const float* ar2 = (const float*)d_in[8];
    float* out = (float*)d_out;

    const int N = in_sizes[0] / FDIM;
    const int E = in_sizes[1];

    float* A  = (float*)d_ws;
    float* B  = A + (size_t)N * FDIM;
    float* el = B + (size_t)N * FDIM;
    float* er = el + (size_t)N * HEADS;
    float* val = er + (size_t)N * HEADS;     // 1024 f32
    int* counts  = (int*)(val + 1024);
    int* offsets = counts + N;
    int* cursor  = offsets + (N + 1);
    int* csr_src = cursor + N;
    int* bsums   = csr_src + E;
    uintptr_t wp = ((uintptr_t)(bsums + 256) + 63) & ~(uintptr_t)63;
    __bf16* wf1   = (__bf16*)wp;             // 32768 bf16
    __bf16* wext1 = wf1 + 32768;             // 4096 bf16
    __bf16* wf2   = wext1 + 4096;
    __bf16* wext2 = wf2 + 32768;

    const int ntiles = (N + 63) / 64;
    const int gemm_grid = ntiles < 512 ? ntiles : 512;
    const int edge_grid = (E + 255) / 256;
    const int agg_grid  = ((N + 3) / 4 + 3) / 4;   // 4 nodes/wave, 4 waves/block
    const int nscan     = (N + 1023) / 1024;

    // ---- W preprocessing (once per layer) ----
    valcomp_kernel<<<1, 512, 0, stream>>>(W1, al1, ar1, val);
    wfrag_kernel<<<128, 256, 0, stream>>>(W1, wf1);
    wext_kernel<<<16, 256, 0, stream>>>(val, wext1);
    valcomp_kernel<<<1, 512, 0, stream>>>(W2, al2, ar2, val);
    wfrag_kernel<<<128, 256, 0, stream>>>(W2, wf2);
    wext_kernel<<<16, 256, 0, stream>>>(val, wext2);

    // ---- CSR build (once; shared by both layers) ----
    hipMemsetAsync(counts, 0, (size_t)N * sizeof(int), stream);
    hist_kernel<<<edge_grid, 256, 0, stream>>>(dst, counts, E);
    scan1_kernel<<<nscan, 256, 0, stream>>>(counts, offsets, bsums, N);
    scan2_kernel<<<1, 64, 0, stream>>>(bsums, nscan);
    scan3_kernel<<<nscan, 256, 0, stream>>>(offsets, cursor, bsums, N, E);
    scatter_kernel<<<edge_grid, 256, 0, stream>>>(src, dst, cursor, csr_src, E);

    // ---- layer 1 ----
    gemm_mfma_kernel<<<gemm_grid, 256, 0, stream>>>(
        x, (const bf16x8*)wf1, (const bf16x8*)wext1, A, el, er, N, ntiles);
    aggregate_kernel<false><<<agg_grid, 256, 0, stream>>>(A, el, er, offsets, csr_src, B, N);

    // ---- layer 2 ----
    gemm_mfma_kernel<<<gemm_grid, 256, 0, stream>>>(
        B, (const bf16x8*)wf2, (const bf16x8*)wext2, A, el, er, N, ntiles);
    aggregate_kernel<true><<<agg_grid, 256, 0, stream>>>(A, el, er, offsets, csr_src, out, N);
}

// Round 6
// 296.907 us; speedup vs baseline: 3.7525x; 1.2162x over previous
//
#include <hip/hip_runtime.h>
#include <cmath>

#define HEADS 4
#define FDIM 128   // H*D == IN_DIM == 128
#define NEG 0.2f

typedef __attribute__((ext_vector_type(8))) __bf16 bf16x8;
typedef __attribute__((ext_vector_type(8))) _Float16 h16x8;
typedef __attribute__((ext_vector_type(4))) float f32x4;

// ---------------------------------------------------------------------------
// Unified W preprocessing, one dispatch:
//   blocks 0..127   : wfrag for W1   (frag-ordered split-bf16 image, 32768 el)
//   blocks 128..255 : wfrag for W2
//   block 256       : valcomp+wext for W1 (el/er B-tile, 4096 el)
//   block 257       : valcomp+wext for W2
// wf layout:  wf[((hl*16+kq)*8 + t)*16 + c][j] = hi/lo of W[(t*16+c)*128+kq*8+j]
// wext layout: wext[(hl*16+kq)*16 + c][j] = hi/lo of val[c][kq*8+j], c<8 else 0
//   val[c][k] = sum_d al[c,d]*W[c*32+d][k] (c<4) / ar[c-4,d]*... (c>=4)
// ---------------------------------------------------------------------------
__global__ __launch_bounds__(256) void prep_kernel(
    const float* __restrict__ W1, const float* __restrict__ al1,
    const float* __restrict__ ar1,
    const float* __restrict__ W2, const float* __restrict__ al2,
    const float* __restrict__ ar2,
    __bf16* __restrict__ wf1, __bf16* __restrict__ wext1,
    __bf16* __restrict__ wf2, __bf16* __restrict__ wext2)
{
    const int b = blockIdx.x, tid = threadIdx.x;
    if (b < 256) {
        const float* W = (b < 128) ? W1 : W2;
        __bf16* wf = (b < 128) ? wf1 : wf2;
        int idx = (b & 127) * 256 + tid;        // < 32768
        int j = idx & 7;
        int r = idx >> 3;
        int c = r & 15; r >>= 4;
        int t = r & 7;  r >>= 3;
        int kq = r & 15;
        int hl = r >> 4;
        float v = W[(t * 16 + c) * 128 + kq * 8 + j];
        __bf16 hi = (__bf16)v;
        wf[idx] = (hl == 0) ? hi : (__bf16)(v - (float)hi);
    } else {
        const float* W  = (b == 256) ? W1 : W2;
        const float* al = (b == 256) ? al1 : al2;
        const float* ar = (b == 256) ? ar1 : ar2;
        __bf16* wext = (b == 256) ? wext1 : wext2;
        __shared__ float val[1024];
        #pragma unroll
        for (int ch = 0; ch < 4; ++ch) {
            int idx = ch * 256 + tid;           // < 1024
            int c = idx >> 7, k = idx & 127;
            int h = c & 3;
            const float* a = (c < 4) ? al : ar;
            float s = 0.f;
            for (int d = 0; d < 32; ++d)
                s += a[h * 32 + d] * W[(h * 32 + d) * 128 + k];
            val[c * 128 + k] = s;
        }
        __syncthreads();
        #pragma unroll
        for (int ch = 0; ch < 16; ++ch) {
            int idx = tid * 16 + ch;            // < 4096
            int j = idx & 7;
            int r = idx >> 3;
            int c = r & 15; r >>= 4;
            int kq = r & 15;
            int hl = r >> 4;
            float v = (c < 8) ? val[c * 128 + kq * 8 + j] : 0.f;
            __bf16 hi = (__bf16)v;
            wext[idx] = (hl == 0) ? hi : (__bf16)(v - (float)hi);
        }
    }
}

// ---------------------------------------------------------------------------
// MFMA GEMM, LDS-staged W (64 KB), grid-stride tiles, X reg-prefetch.
// A[m=lane&15][k=quad*8+j], B[k=quad*8+j][n=lane&15], D[row=quad*4+r][col=lane&15].
// acc[0..7] = feat cols (stored fp16), acc[8] = el (cols 0-3) / er (cols 4-7).
// ---------------------------------------------------------------------------
__global__ __launch_bounds__(256) void gemm_mfma_kernel(
    const float* __restrict__ X, const bf16x8* __restrict__ wf,
    const bf16x8* __restrict__ wext,
    _Float16* __restrict__ featH,
    float* __restrict__ el, float* __restrict__ er,
    int nnodes, int ntiles)
{
    __shared__ bf16x8 lw[4096];   // 65536 B
    const int tid = threadIdx.x;
    for (int i = tid; i < 4096; i += 256) lw[i] = wf[i];
    __syncthreads();

    const int wave = tid >> 6, lane = tid & 63;
    const int l15 = lane & 15, quad = lane >> 4;

    int tile = blockIdx.x;
    float4 xr[8], xn[8];

    auto loadX = [&](int tl, float4* dst) {
        int nodeA = tl * 64 + wave * 16 + l15;
        bool v = nodeA < nnodes;
        const float4* xp = (const float4*)(X + (size_t)nodeA * 128);
        #pragma unroll
        for (int ks = 0; ks < 4; ++ks) {
            dst[2 * ks]     = v ? xp[ks * 8 + quad * 2]     : make_float4(0.f, 0.f, 0.f, 0.f);
            dst[2 * ks + 1] = v ? xp[ks * 8 + quad * 2 + 1] : make_float4(0.f, 0.f, 0.f, 0.f);
        }
    };

    loadX(tile, xr);
    while (true) {
        int next = tile + gridDim.x;
        if (next < ntiles) loadX(next, xn);

        f32x4 acc[9];
        #pragma unroll
        for (int t = 0; t < 9; ++t) acc[t] = (f32x4){0.f, 0.f, 0.f, 0.f};

        #pragma unroll
        for (int ks = 0; ks < 4; ++ks) {
            float xa[8] = {xr[2 * ks].x, xr[2 * ks].y, xr[2 * ks].z, xr[2 * ks].w,
                           xr[2 * ks + 1].x, xr[2 * ks + 1].y, xr[2 * ks + 1].z, xr[2 * ks + 1].w};
            bf16x8 ahi, alo;
            #pragma unroll
            for (int j = 0; j < 8; ++j) {
                __bf16 h = (__bf16)xa[j];
                ahi[j] = h;
                alo[j] = (__bf16)(xa[j] - (float)h);
            }
            const int kq = ks * 4 + quad;

            {
                bf16x8 bh = wext[(kq) * 16 + l15];
                bf16x8 bl = wext[(16 + kq) * 16 + l15];
                acc[8] = __builtin_amdgcn_mfma_f32_16x16x32_bf16(ahi, bh, acc[8], 0, 0, 0);
                acc[8] = __builtin_amdgcn_mfma_f32_16x16x32_bf16(alo, bh, acc[8], 0, 0, 0);
                acc[8] = __builtin_amdgcn_mfma_f32_16x16x32_bf16(ahi, bl, acc[8], 0, 0, 0);
            }
            #pragma unroll
            for (int t = 0; t < 8; ++t) {
                bf16x8 bh = lw[(kq * 8 + t) * 16 + l15];
                bf16x8 bl = lw[((16 + kq) * 8 + t) * 16 + l15];
                acc[t] = __builtin_amdgcn_mfma_f32_16x16x32_bf16(ahi, bh, acc[t], 0, 0, 0);
                acc[t] = __builtin_amdgcn_mfma_f32_16x16x32_bf16(alo, bh, acc[t], 0, 0, 0);
                acc[t] = __builtin_amdgcn_mfma_f32_16x16x32_bf16(ahi, bl, acc[t], 0, 0, 0);
            }
        }

        const int nodeC = tile * 64 + wave * 16 + quad * 4;
        #pragma unroll
        for (int r = 0; r < 4; ++r) {
            int gn = nodeC + r;
            if (gn < nnodes) {
                #pragma unroll
                for (int t = 0; t < 8; ++t)
                    featH[(size_t)gn * 128 + t * 16 + l15] = (_Float16)acc[t][r];
            }
        }
        if (l15 < 8) {
            #pragma unroll
            for (int r = 0; r < 4; ++r) {
                int gn = nodeC + r;
                if (gn < nnodes) {
                    if (l15 < 4) el[gn * HEADS + l15] = acc[8][r];
                    else         er[gn * HEADS + (l15 - 4)] = acc[8][r];
                }
            }
        }

        if (next >= ntiles) break;
        #pragma unroll
        for (int i = 0; i < 8; ++i) xr[i] = xn[i];
        tile = next;
    }
}

// ---------------------------------------------------------------------------
// CSR build: histogram -> 3-kernel hierarchical exclusive scan -> scatter.
// ---------------------------------------------------------------------------
__global__ __launch_bounds__(256) void hist_kernel(
    const int* __restrict__ dst, int* __restrict__ counts, int nedges)
{
    int i = blockIdx.x * 256 + threadIdx.x;
    if (i < nedges) atomicAdd(&counts[dst[i]], 1);
}

__global__ __launch_bounds__(256) void scan1_kernel(
    const int* __restrict__ counts, int* __restrict__ offsets,
    int* __restrict__ bsums, int n)
{
    __shared__ int wsums[4];
    const int tid = threadIdx.x, lane = tid & 63, w = tid >> 6;
    const int i = blockIdx.x * 1024 + tid * 4;

    int4 v = make_int4(0, 0, 0, 0);
    if (i + 3 < n) v = *(const int4*)&counts[i];
    else {
        if (i < n)     v.x = counts[i];
        if (i + 1 < n) v.y = counts[i + 1];
        if (i + 2 < n) v.z = counts[i + 2];
    }
    int s0 = v.x, s1 = s0 + v.y, s2 = s1 + v.z, s3 = s2 + v.w;

    int x = s3;
    #pragma unroll
    for (int off = 1; off < 64; off <<= 1) {
        int t = __shfl_up(x, off, 64);
        if (lane >= off) x += t;
    }
    if (lane == 63) wsums[w] = x;
    __syncthreads();
    int wbase = 0;
    #pragma unroll
    for (int k = 0; k < 4; ++k) if (k < w) wbase += wsums[k];

    int tbase = wbase + x - s3;
    if (i < n)     offsets[i]     = tbase;
    if (i + 1 < n) offsets[i + 1] = tbase + s0;
    if (i + 2 < n) offsets[i + 2] = tbase + s1;
    if (i + 3 < n) offsets[i + 3] = tbase + s2;
    if (tid == 255) bsums[blockIdx.x] = wbase + x;
}

__global__ __launch_bounds__(64) void scan2_kernel(int* __restrict__ bsums, int nb)
{
    const int lane = threadIdx.x;
    int run = 0;
    for (int base = 0; base < nb; base += 64) {
        int i = base + lane;
        int v = (i < nb) ? bsums[i] : 0;
        int x = v;
        #pragma unroll
        for (int off = 1; off < 64; off <<= 1) {
            int t = __shfl_up(x, off, 64);
            if (lane >= off) x += t;
        }
        if (i < nb) bsums[i] = run + x - v;
        run += __shfl(x, 63, 64);
    }
}

__global__ __launch_bounds__(256) void scan3_kernel(
    int* __restrict__ offsets, int* __restrict__ cursor,
    const int* __restrict__ bsums, int n, int nedges)
{
    const int i = blockIdx.x * 1024 + threadIdx.x * 4;
    const int base = bsums[blockIdx.x];
    #pragma unroll
    for (int k = 0; k < 4; ++k) {
        if (i + k < n) {
            int o = offsets[i + k] + base;
            offsets[i + k] = o;
            cursor[i + k] = o;
        }
    }
    if (blockIdx.x == 0 && threadIdx.x == 0) offsets[n] = nedges;
}

__global__ __launch_bounds__(256) void scatter_kernel(
    const int* __restrict__ src, const int* __restrict__ dst,
    int* __restrict__ cursor, int* __restrict__ csr_src, int nedges)
{
    int i = blockIdx.x * 256 + threadIdx.x;
    if (i < nedges) {
        int pos = atomicAdd(&cursor[dst[i]], 1);
        csr_src[pos] = src[i];
    }
}

// ---------------------------------------------------------------------------
// Gather aggregation: 4 dst nodes per wave, 16 lanes/node, 8 fp16 feats/lane
// (one dwordx4 per edge per lane). f32 accumulate. Depth-1 SW pipeline.
// ---------------------------------------------------------------------------
template <bool MEAN>
__global__ __launch_bounds__(256) void aggregate_kernel(
    const _Float16* __restrict__ featH, const float* __restrict__ el,
    const float* __restrict__ er, const int* __restrict__ offsets,
    const int* __restrict__ csr_src, float* __restrict__ out, int nnodes)
{
    const int wid = (blockIdx.x * 256 + threadIdx.x) >> 6;
    const int lane = threadIdx.x & 63;
    const int g = lane >> 4, u = lane & 15, h = u >> 2;
    const int n = wid * 4 + g;
    const bool nv = n < nnodes;

    int beg = 0, end = 0;
    float ern = 0.f;
    if (nv) {
        beg = offsets[n];
        end = offsets[n + 1];
        ern = er[n * HEADS + h];
    }
    int md = end - beg;
    md = max(md, __shfl_xor(md, 16, 64));
    md = max(md, __shfl_xor(md, 32, 64));

    float a[8];
    #pragma unroll
    for (int p = 0; p < 8; ++p) a[p] = 0.f;
    float sw = 0.f;

    int j = beg;
    bool v = j < end;
    int s = v ? csr_src[j] : 0;
    float q = el[s * HEADS + h];
    h16x8 f = ((const h16x8*)(featH + (size_t)s * 128))[u];

    for (int it = 0; it < md; ++it) {
        int jn = j + 1;
        bool vn = jn < end;
        int sn = vn ? csr_src[jn] : 0;
        float qn = el[sn * HEADS + h];
        h16x8 fn = ((const h16x8*)(featH + (size_t)sn * 128))[u];

        float e = q + ern;
        e = e > 0.f ? e : NEG * e;
        float w = v ? __expf(e) : 0.f;
        #pragma unroll
        for (int p = 0; p < 8; ++p) a[p] += w * (float)f[p];
        sw += w;

        j = jn; v = vn; q = qn; f = fn;
    }

    float inv = sw > 0.f ? 1.f / sw : 0.f;
    float r[8];
    #pragma unroll
    for (int p = 0; p < 8; ++p) {
        float t = a[p] * inv;
        r[p] = t > 0.f ? t : expm1f(t);
    }

    if (!MEAN) {
        if (nv) {
            float4* o4 = (float4*)(out + (size_t)n * 128 + u * 8);
            o4[0] = make_float4(r[0], r[1], r[2], r[3]);
            o4[1] = make_float4(r[4], r[5], r[6], r[7]);
        }
    } else {
        #pragma unroll
        for (int p = 0; p < 8; ++p) {
            r[p] += __shfl_xor(r[p], 4, 64);
            r[p] += __shfl_xor(r[p], 8, 64);
        }
        if (nv && u < 4) {
            float4* o4 = (float4*)(out + (size_t)n * 32 + u * 8);
            o4[0] = make_float4(0.25f * r[0], 0.25f * r[1], 0.25f * r[2], 0.25f * r[3]);
            o4[1] = make_float4(0.25f * r[4], 0.25f * r[5], 0.25f * r[6], 0.25f * r[7]);
        }
    }
}

// ---------------------------------------------------------------------------
extern "C" void kernel_launch(void* const* d_in, const int* in_sizes, int n_in,
                              void* d_out, int out_size, void* d_ws, size_t ws_size,
                              hipStream_t stream)
{
    const float* x   = (const float*)d_in[0];
    const int*   src = (const int*)d_in[1];
    const int*   dst = (const int*)d_in[2];
    const float* W1  = (const float*)d_in[3];
    const float* al1 = (const float*)d_in[4];
    const float* ar1 = (const float*)d_in[5];
    const float* W2  = (const float*)d_in[6];
    const float* al2 = (const float*)d_in[7];
    const float* ar2 = (const float*)d_in[8];
    float* out = (float*)d_out;

    const int N = in_sizes[0] / FDIM;
    const int E = in_sizes[1];

    // workspace: h1[N*128] f32 | featH[N*128] fp16 | el[N*4] | er[N*4] |
    //            counts[N] | offsets[N+1] | cursor[N] | csr_src[E] |
    //            bsums[256] | wf1|wext1|wf2|wext2
    float* h1 = (float*)d_ws;
    _Float16* featH = (_Float16*)(h1 + (size_t)N * FDIM);
    float* el = (float*)(featH + (size_t)N * FDIM);
    float* er = el + (size_t)N * HEADS;
    int* counts  = (int*)(er + (size_t)N * HEADS);
    int* offsets = counts + N;
    int* cursor  = offsets + (N + 1);
    int* csr_src = cursor + N;
    int* bsums   = csr_src + E;
    uintptr_t wp = ((uintptr_t)(bsums + 256) + 63) & ~(uintptr_t)63;
    __bf16* wf1   = (__bf16*)wp;             // 32768 bf16
    __bf16* wext1 = wf1 + 32768;             // 4096 bf16
    __bf16* wf2   = wext1 + 4096;
    __bf16* wext2 = wf2 + 32768;

    const int ntiles = (N + 63) / 64;
    const int gemm_grid = ntiles < 512 ? ntiles : 512;
    const int edge_grid = (E + 255) / 256;
    const int agg_grid  = ((N + 3) / 4 + 3) / 4;   // 4 nodes/wave, 4 waves/block
    const int nscan     = (N + 1023) / 1024;

    // ---- W preprocessing (one dispatch) ----
    prep_kernel<<<258, 256, 0, stream>>>(W1, al1, ar1, W2, al2, ar2,
                                         wf1, wext1, wf2, wext2);

    // ---- CSR build (once; shared by both layers) ----
    hipMemsetAsync(counts, 0, (size_t)N * sizeof(int), stream);
    hist_kernel<<<edge_grid, 256, 0, stream>>>(dst, counts, E);
    scan1_kernel<<<nscan, 256, 0, stream>>>(counts, offsets, bsums, N);
    scan2_kernel<<<1, 64, 0, stream>>>(bsums, nscan);
    scan3_kernel<<<nscan, 256, 0, stream>>>(offsets, cursor, bsums, N, E);
    scatter_kernel<<<edge_grid, 256, 0, stream>>>(src, dst, cursor, csr_src, E);

    // ---- layer 1 ----
    gemm_mfma_kernel<<<gemm_grid, 256, 0, stream>>>(
        x, (const bf16x8*)wf1, (const bf16x8*)wext1, featH, el, er, N, ntiles);
    aggregate_kernel<false><<<agg_grid, 256, 0, stream>>>(
        featH, el, er, offsets, csr_src, h1, N);

    // ---- layer 2 ----
    gemm_mfma_kernel<<<gemm_grid, 256, 0, stream>>>(
        h1, (const bf16x8*)wf2, (const bf16x8*)wext2, featH, el, er, N, ntiles);
    aggregate_kernel<true><<<agg_grid, 256, 0, stream>>>(
        featH, el, er, offsets, csr_src, out, N);
}

// Round 7
// 257.876 us; speedup vs baseline: 4.3204x; 1.1514x over previous
//
#include <hip/hip_runtime.h>
#include <cmath>

#define HEADS 4
#define FDIM 128   // H*D == IN_DIM == 128
#define NEG 0.2f

typedef __attribute__((ext_vector_type(8))) __bf16 bf16x8;
typedef __attribute__((ext_vector_type(8))) _Float16 h16x8;
typedef __attribute__((ext_vector_type(4))) float f32x4;

// ---------------------------------------------------------------------------
// Unified W preprocessing, one dispatch (see r5 notes for layouts).
// ---------------------------------------------------------------------------
__global__ __launch_bounds__(256) void prep_kernel(
    const float* __restrict__ W1, const float* __restrict__ al1,
    const float* __restrict__ ar1,
    const float* __restrict__ W2, const float* __restrict__ al2,
    const float* __restrict__ ar2,
    __bf16* __restrict__ wf1, __bf16* __restrict__ wext1,
    __bf16* __restrict__ wf2, __bf16* __restrict__ wext2)
{
    const int b = blockIdx.x, tid = threadIdx.x;
    if (b < 256) {
        const float* W = (b < 128) ? W1 : W2;
        __bf16* wf = (b < 128) ? wf1 : wf2;
        int idx = (b & 127) * 256 + tid;        // < 32768
        int j = idx & 7;
        int r = idx >> 3;
        int c = r & 15; r >>= 4;
        int t = r & 7;  r >>= 3;
        int kq = r & 15;
        int hl = r >> 4;
        float v = W[(t * 16 + c) * 128 + kq * 8 + j];
        __bf16 hi = (__bf16)v;
        wf[idx] = (hl == 0) ? hi : (__bf16)(v - (float)hi);
    } else {
        const float* W  = (b == 256) ? W1 : W2;
        const float* al = (b == 256) ? al1 : al2;
        const float* ar = (b == 256) ? ar1 : ar2;
        __bf16* wext = (b == 256) ? wext1 : wext2;
        __shared__ float val[1024];
        #pragma unroll
        for (int ch = 0; ch < 4; ++ch) {
            int idx = ch * 256 + tid;           // < 1024
            int c = idx >> 7, k = idx & 127;
            int h = c & 3;
            const float* a = (c < 4) ? al : ar;
            float s = 0.f;
            for (int d = 0; d < 32; ++d)
                s += a[h * 32 + d] * W[(h * 32 + d) * 128 + k];
            val[c * 128 + k] = s;
        }
        __syncthreads();
        #pragma unroll
        for (int ch = 0; ch < 16; ++ch) {
            int idx = tid * 16 + ch;            // < 4096
            int j = idx & 7;
            int r = idx >> 3;
            int c = r & 15; r >>= 4;
            int kq = r & 15;
            int hl = r >> 4;
            float v = (c < 8) ? val[c * 128 + kq * 8 + j] : 0.f;
            __bf16 hi = (__bf16)v;
            wext[idx] = (hl == 0) ? hi : (__bf16)(v - (float)hi);
        }
    }
}

// ---------------------------------------------------------------------------
// MFMA GEMM, LDS-staged W (64 KB), grid-stride tiles, X reg-prefetch.
// acc[0..7] = feat cols (stored fp16), acc[8] = el (cols 0-3) / er (cols 4-7).
// ---------------------------------------------------------------------------
__global__ __launch_bounds__(256) void gemm_mfma_kernel(
    const float* __restrict__ X, const bf16x8* __restrict__ wf,
    const bf16x8* __restrict__ wext,
    _Float16* __restrict__ featH,
    float* __restrict__ el, float* __restrict__ er,
    int nnodes, int ntiles)
{
    __shared__ bf16x8 lw[4096];   // 65536 B
    const int tid = threadIdx.x;
    for (int i = tid; i < 4096; i += 256) lw[i] = wf[i];
    __syncthreads();

    const int wave = tid >> 6, lane = tid & 63;
    const int l15 = lane & 15, quad = lane >> 4;

    int tile = blockIdx.x;
    float4 xr[8], xn[8];

    auto loadX = [&](int tl, float4* dst) {
        int nodeA = tl * 64 + wave * 16 + l15;
        bool v = nodeA < nnodes;
        const float4* xp = (const float4*)(X + (size_t)nodeA * 128);
        #pragma unroll
        for (int ks = 0; ks < 4; ++ks) {
            dst[2 * ks]     = v ? xp[ks * 8 + quad * 2]     : make_float4(0.f, 0.f, 0.f, 0.f);
            dst[2 * ks + 1] = v ? xp[ks * 8 + quad * 2 + 1] : make_float4(0.f, 0.f, 0.f, 0.f);
        }
    };

    loadX(tile, xr);
    while (true) {
        int next = tile + gridDim.x;
        if (next < ntiles) loadX(next, xn);

        f32x4 acc[9];
        #pragma unroll
        for (int t = 0; t < 9; ++t) acc[t] = (f32x4){0.f, 0.f, 0.f, 0.f};

        #pragma unroll
        for (int ks = 0; ks < 4; ++ks) {
            float xa[8] = {xr[2 * ks].x, xr[2 * ks].y, xr[2 * ks].z, xr[2 * ks].w,
                           xr[2 * ks + 1].x, xr[2 * ks + 1].y, xr[2 * ks + 1].z, xr[2 * ks + 1].w};
            bf16x8 ahi, alo;
            #pragma unroll
            for (int j = 0; j < 8; ++j) {
                __bf16 h = (__bf16)xa[j];
                ahi[j] = h;
                alo[j] = (__bf16)(xa[j] - (float)h);
            }
            const int kq = ks * 4 + quad;

            {
                bf16x8 bh = wext[(kq) * 16 + l15];
                bf16x8 bl = wext[(16 + kq) * 16 + l15];
                acc[8] = __builtin_amdgcn_mfma_f32_16x16x32_bf16(ahi, bh, acc[8], 0, 0, 0);
                acc[8] = __builtin_amdgcn_mfma_f32_16x16x32_bf16(alo, bh, acc[8], 0, 0, 0);
                acc[8] = __builtin_amdgcn_mfma_f32_16x16x32_bf16(ahi, bl, acc[8], 0, 0, 0);
            }
            #pragma unroll
            for (int t = 0; t < 8; ++t) {
                bf16x8 bh = lw[(kq * 8 + t) * 16 + l15];
                bf16x8 bl = lw[((16 + kq) * 8 + t) * 16 + l15];
                acc[t] = __builtin_amdgcn_mfma_f32_16x16x32_bf16(ahi, bh, acc[t], 0, 0, 0);
                acc[t] = __builtin_amdgcn_mfma_f32_16x16x32_bf16(alo, bh, acc[t], 0, 0, 0);
                acc[t] = __builtin_amdgcn_mfma_f32_16x16x32_bf16(ahi, bl, acc[t], 0, 0, 0);
            }
        }

        const int nodeC = tile * 64 + wave * 16 + quad * 4;
        #pragma unroll
        for (int r = 0; r < 4; ++r) {
            int gn = nodeC + r;
            if (gn < nnodes) {
                #pragma unroll
                for (int t = 0; t < 8; ++t)
                    featH[(size_t)gn * 128 + t * 16 + l15] = (_Float16)acc[t][r];
            }
        }
        if (l15 < 8) {
            #pragma unroll
            for (int r = 0; r < 4; ++r) {
                int gn = nodeC + r;
                if (gn < nnodes) {
                    if (l15 < 4) el[gn * HEADS + l15] = acc[8][r];
                    else         er[gn * HEADS + (l15 - 4)] = acc[8][r];
                }
            }
        }

        if (next >= ntiles) break;
        #pragma unroll
        for (int i = 0; i < 8; ++i) xr[i] = xn[i];
        tile = next;
    }
}

// ---------------------------------------------------------------------------
// CSR build. hist captures each edge's within-segment rank from the atomic's
// return value (the scatter pass then needs NO atomics).
// ---------------------------------------------------------------------------
__global__ __launch_bounds__(256) void hist_kernel(
    const int* __restrict__ dst, int* __restrict__ counts,
    int* __restrict__ rank, int nedges)
{
    int i0 = (blockIdx.x * 256 + threadIdx.x) * 4;
    if (i0 + 3 < nedges) {
        int4 d = *(const int4*)&dst[i0];
        int4 r;
        r.x = atomicAdd(&counts[d.x], 1);
        r.y = atomicAdd(&counts[d.y], 1);
        r.z = atomicAdd(&counts[d.z], 1);
        r.w = atomicAdd(&counts[d.w], 1);
        *(int4*)&rank[i0] = r;
    } else {
        for (int i = i0; i < nedges; ++i)
            rank[i] = atomicAdd(&counts[dst[i]], 1);
    }
}

__global__ __launch_bounds__(256) void scan1_kernel(
    const int* __restrict__ counts, int* __restrict__ offsets,
    int* __restrict__ bsums, int n)
{
    __shared__ int wsums[4];
    const int tid = threadIdx.x, lane = tid & 63, w = tid >> 6;
    const int i = blockIdx.x * 1024 + tid * 4;

    int4 v = make_int4(0, 0, 0, 0);
    if (i + 3 < n) v = *(const int4*)&counts[i];
    else {
        if (i < n)     v.x = counts[i];
        if (i + 1 < n) v.y = counts[i + 1];
        if (i + 2 < n) v.z = counts[i + 2];
    }
    int s0 = v.x, s1 = s0 + v.y, s2 = s1 + v.z, s3 = s2 + v.w;

    int x = s3;
    #pragma unroll
    for (int off = 1; off < 64; off <<= 1) {
        int t = __shfl_up(x, off, 64);
        if (lane >= off) x += t;
    }
    if (lane == 63) wsums[w] = x;
    __syncthreads();
    int wbase = 0;
    #pragma unroll
    for (int k = 0; k < 4; ++k) if (k < w) wbase += wsums[k];

    int tbase = wbase + x - s3;
    if (i < n)     offsets[i]     = tbase;
    if (i + 1 < n) offsets[i + 1] = tbase + s0;
    if (i + 2 < n) offsets[i + 2] = tbase + s1;
    if (i + 3 < n) offsets[i + 3] = tbase + s2;
    if (tid == 255) bsums[blockIdx.x] = wbase + x;
}

__global__ __launch_bounds__(64) void scan2_kernel(int* __restrict__ bsums, int nb)
{
    const int lane = threadIdx.x;
    int run = 0;
    for (int base = 0; base < nb; base += 64) {
        int i = base + lane;
        int v = (i < nb) ? bsums[i] : 0;
        int x = v;
        #pragma unroll
        for (int off = 1; off < 64; off <<= 1) {
            int t = __shfl_up(x, off, 64);
            if (lane >= off) x += t;
        }
        if (i < nb) bsums[i] = run + x - v;
        run += __shfl(x, 63, 64);
    }
}

__global__ __launch_bounds__(256) void scan3_kernel(
    int* __restrict__ offsets, const int* __restrict__ bsums, int n, int nedges)
{
    const int i = blockIdx.x * 1024 + threadIdx.x * 4;
    const int base = bsums[blockIdx.x];
    #pragma unroll
    for (int k = 0; k < 4; ++k)
        if (i + k < n) offsets[i + k] += base;
    if (blockIdx.x == 0 && threadIdx.x == 0) offsets[n] = nedges;
}

// atomic-free scatter: pos = offsets[dst] + rank
__global__ __launch_bounds__(256) void scatter_kernel(
    const int* __restrict__ src, const int* __restrict__ dst,
    const int* __restrict__ rank, const int* __restrict__ offsets,
    int* __restrict__ csr_src, int nedges)
{
    int i0 = (blockIdx.x * 256 + threadIdx.x) * 4;
    if (i0 + 3 < nedges) {
        int4 d = *(const int4*)&dst[i0];
        int4 r = *(const int4*)&rank[i0];
        int4 s = *(const int4*)&src[i0];
        csr_src[offsets[d.x] + r.x] = s.x;
        csr_src[offsets[d.y] + r.y] = s.y;
        csr_src[offsets[d.z] + r.z] = s.z;
        csr_src[offsets[d.w] + r.w] = s.w;
    } else {
        for (int i = i0; i < nedges; ++i)
            csr_src[offsets[dst[i]] + rank[i]] = src[i];
    }
}

// ---------------------------------------------------------------------------
// Gather aggregation: 4 dst nodes per wave, 16 lanes/node, 8 fp16 feats/lane.
// ---------------------------------------------------------------------------
template <bool MEAN>
__global__ __launch_bounds__(256) void aggregate_kernel(
    const _Float16* __restrict__ featH, const float* __restrict__ el,
    const float* __restrict__ er, const int* __restrict__ offsets,
    const int* __restrict__ csr_src, float* __restrict__ out, int nnodes)
{
    const int wid = (blockIdx.x * 256 + threadIdx.x) >> 6;
    const int lane = threadIdx.x & 63;
    const int g = lane >> 4, u = lane & 15, h = u >> 2;
    const int n = wid * 4 + g;
    const bool nv = n < nnodes;

    int beg = 0, end = 0;
    float ern = 0.f;
    if (nv) {
        beg = offsets[n];
        end = offsets[n + 1];
        ern = er[n * HEADS + h];
    }
    int md = end - beg;
    md = max(md, __shfl_xor(md, 16, 64));
    md = max(md, __shfl_xor(md, 32, 64));

    float a[8];
    #pragma unroll
    for (int p = 0; p < 8; ++p) a[p] = 0.f;
    float sw = 0.f;

    int j = beg;
    bool v = j < end;
    int s = v ? csr_src[j] : 0;
    float q = el[s * HEADS + h];
    h16x8 f = ((const h16x8*)(featH + (size_t)s * 128))[u];

    for (int it = 0; it < md; ++it) {
        int jn = j + 1;
        bool vn = jn < end;
        int sn = vn ? csr_src[jn] : 0;
        float qn = el[sn * HEADS + h];
        h16x8 fn = ((const h16x8*)(featH + (size_t)sn * 128))[u];

        float e = q + ern;
        e = e > 0.f ? e : NEG * e;
        float w = v ? __expf(e) : 0.f;
        #pragma unroll
        for (int p = 0; p < 8; ++p) a[p] += w * (float)f[p];
        sw += w;

        j = jn; v = vn; q = qn; f = fn;
    }

    float inv = sw > 0.f ? 1.f / sw : 0.f;
    float r[8];
    #pragma unroll
    for (int p = 0; p < 8; ++p) {
        float t = a[p] * inv;
        r[p] = t > 0.f ? t : expm1f(t);
    }

    if (!MEAN) {
        if (nv) {
            float4* o4 = (float4*)(out + (size_t)n * 128 + u * 8);
            o4[0] = make_float4(r[0], r[1], r[2], r[3]);
            o4[1] = make_float4(r[4], r[5], r[6], r[7]);
        }
    } else {
        #pragma unroll
        for (int p = 0; p < 8; ++p) {
            r[p] += __shfl_xor(r[p], 4, 64);
            r[p] += __shfl_xor(r[p], 8, 64);
        }
        if (nv && u < 4) {
            float4* o4 = (float4*)(out + (size_t)n * 32 + u * 8);
            o4[0] = make_float4(0.25f * r[0], 0.25f * r[1], 0.25f * r[2], 0.25f * r[3]);
            o4[1] = make_float4(0.25f * r[4], 0.25f * r[5], 0.25f * r[6], 0.25f * r[7]);
        }
    }
}

// ---------------------------------------------------------------------------
extern "C" void kernel_launch(void* const* d_in, const int* in_sizes, int n_in,
                              void* d_out, int out_size, void* d_ws, size_t ws_size,
                              hipStream_t stream)
{
    const float* x   = (const float*)d_in[0];
    const int*   src = (const int*)d_in[1];
    const int*   dst = (const int*)d_in[2];
    const float* W1  = (const float*)d_in[3];
    const float* al1 = (const float*)d_in[4];
    const float* ar1 = (const float*)d_in[5];
    const float* W2  = (const float*)d_in[6];
    const float* al2 = (const float*)d_in[7];
    const float* ar2 = (const float*)d_in[8];
    float* out = (float*)d_out;

    const int N = in_sizes[0] / FDIM;
    const int E = in_sizes[1];

    // workspace: h1[N*128] f32 | featH[N*128] fp16 | el[N*4] | er[N*4] |
    //            counts[N] | offsets[N+1] | rank[E] | csr_src[E] |
    //            bsums[256] | wf1|wext1|wf2|wext2
    float* h1 = (float*)d_ws;
    _Float16* featH = (_Float16*)(h1 + (size_t)N * FDIM);
    float* el = (float*)(featH + (size_t)N * FDIM);
    float* er = el + (size_t)N * HEADS;
    int* counts  = (int*)(er + (size_t)N * HEADS);
    int* offsets = counts + N;
    int* rank    = offsets + (N + 1);
    int* csr_src = rank + E;
    int* bsums   = csr_src + E;
    uintptr_t wp = ((uintptr_t)(bsums + 256) + 63) & ~(uintptr_t)63;
    __bf16* wf1   = (__bf16*)wp;             // 32768 bf16
    __bf16* wext1 = wf1 + 32768;             // 4096 bf16
    __bf16* wf2   = wext1 + 4096;
    __bf16* wext2 = wf2 + 32768;

    const int ntiles = (N + 63) / 64;
    const int gemm_grid = ntiles < 512 ? ntiles : 512;
    const int edge4_grid = ((E + 3) / 4 + 255) / 256;
    const int agg_grid  = ((N + 3) / 4 + 3) / 4;   // 4 nodes/wave, 4 waves/block
    const int nscan     = (N + 1023) / 1024;

    // ---- W preprocessing (one dispatch) ----
    prep_kernel<<<258, 256, 0, stream>>>(W1, al1, ar1, W2, al2, ar2,
                                         wf1, wext1, wf2, wext2);

    // ---- CSR build (once; shared by both layers) ----
    hipMemsetAsync(counts, 0, (size_t)N * sizeof(int), stream);
    hist_kernel<<<edge4_grid, 256, 0, stream>>>(dst, counts, rank, E);
    scan1_kernel<<<nscan, 256, 0, stream>>>(counts, offsets, bsums, N);
    scan2_kernel<<<1, 64, 0, stream>>>(bsums, nscan);
    scan3_kernel<<<nscan, 256, 0, stream>>>(offsets, bsums, N, E);
    scatter_kernel<<<edge4_grid, 256, 0, stream>>>(src, dst, rank, offsets, csr_src, E);

    // ---- layer 1 ----
    gemm_mfma_kernel<<<gemm_grid, 256, 0, stream>>>(
        x, (const bf16x8*)wf1, (const bf16x8*)wext1, featH, el, er, N, ntiles);
    aggregate_kernel<false><<<agg_grid, 256, 0, stream>>>(
        featH, el, er, offsets, csr_src, h1, N);

    // ---- layer 2 ----
    gemm_mfma_kernel<<<gemm_grid, 256, 0, stream>>>(
        h1, (const bf16x8*)wf2, (const bf16x8*)wext2, featH, el, er, N, ntiles);
    aggregate_kernel<true><<<agg_grid, 256, 0, stream>>>(
        featH, el, er, offsets, csr_src, out, N);
}

// Round 9
// 250.042 us; speedup vs baseline: 4.4558x; 1.0313x over previous
//
#include <hip/hip_runtime.h>
#include <cmath>
#include <type_traits>

#define HEADS 4
#define FDIM 128   // H*D == IN_DIM == 128
#define NEG 0.2f
#define NBUCK 8    // src-locality buckets per dst segment

typedef __attribute__((ext_vector_type(8))) __bf16 bf16x8;
typedef __attribute__((ext_vector_type(8))) _Float16 h16x8;
typedef __attribute__((ext_vector_type(4))) float f32x4;

// ---------------------------------------------------------------------------
// Unified W preprocessing, one dispatch (see r5 notes for layouts).
// ---------------------------------------------------------------------------
__global__ __launch_bounds__(256) void prep_kernel(
    const float* __restrict__ W1, const float* __restrict__ al1,
    const float* __restrict__ ar1,
    const float* __restrict__ W2, const float* __restrict__ al2,
    const float* __restrict__ ar2,
    __bf16* __restrict__ wf1, __bf16* __restrict__ wext1,
    __bf16* __restrict__ wf2, __bf16* __restrict__ wext2)
{
    const int b = blockIdx.x, tid = threadIdx.x;
    if (b < 256) {
        const float* W = (b < 128) ? W1 : W2;
        __bf16* wf = (b < 128) ? wf1 : wf2;
        int idx = (b & 127) * 256 + tid;        // < 32768
        int j = idx & 7;
        int r = idx >> 3;
        int c = r & 15; r >>= 4;
        int t = r & 7;  r >>= 3;
        int kq = r & 15;
        int hl = r >> 4;
        float v = W[(t * 16 + c) * 128 + kq * 8 + j];
        __bf16 hi = (__bf16)v;
        wf[idx] = (hl == 0) ? hi : (__bf16)(v - (float)hi);
    } else {
        const float* W  = (b == 256) ? W1 : W2;
        const float* al = (b == 256) ? al1 : al2;
        const float* ar = (b == 256) ? ar1 : ar2;
        __bf16* wext = (b == 256) ? wext1 : wext2;
        __shared__ float val[1024];
        #pragma unroll
        for (int ch = 0; ch < 4; ++ch) {
            int idx = ch * 256 + tid;           // < 1024
            int c = idx >> 7, k = idx & 127;
            int h = c & 3;
            const float* a = (c < 4) ? al : ar;
            float s = 0.f;
            for (int d = 0; d < 32; ++d)
                s += a[h * 32 + d] * W[(h * 32 + d) * 128 + k];
            val[c * 128 + k] = s;
        }
        __syncthreads();
        #pragma unroll
        for (int ch = 0; ch < 16; ++ch) {
            int idx = tid * 16 + ch;            // < 4096
            int j = idx & 7;
            int r = idx >> 3;
            int c = r & 15; r >>= 4;
            int kq = r & 15;
            int hl = r >> 4;
            float v = (c < 8) ? val[c * 128 + kq * 8 + j] : 0.f;
            __bf16 hi = (__bf16)v;
            wext[idx] = (hl == 0) ? hi : (__bf16)(v - (float)hi);
        }
    }
}

// ---------------------------------------------------------------------------
// MFMA GEMM, LDS-staged W (64 KB), grid-stride tiles, X reg-prefetch.
// Templated on input dtype (f32 or fp16; fp16 -> split-bf16 is exact).
// acc[0..7] = feat cols (stored fp16), acc[8] = el (cols 0-3) / er (cols 4-7).
// ---------------------------------------------------------------------------
template <typename XT>
__global__ __launch_bounds__(256) void gemm_mfma_kernel(
    const XT* __restrict__ X, const bf16x8* __restrict__ wf,
    const bf16x8* __restrict__ wext,
    _Float16* __restrict__ featH,
    float* __restrict__ el, float* __restrict__ er,
    int nnodes, int ntiles)
{
    __shared__ bf16x8 lw[4096];   // 65536 B
    const int tid = threadIdx.x;
    for (int i = tid; i < 4096; i += 256) lw[i] = wf[i];
    __syncthreads();

    const int wave = tid >> 6, lane = tid & 63;
    const int l15 = lane & 15, quad = lane >> 4;

    int tile = blockIdx.x;
    float xr[32], xn[32];

    auto loadX = [&](int tl, float* dst) {
        int nodeA = tl * 64 + wave * 16 + l15;
        bool v = nodeA < nnodes;
        if constexpr (std::is_same<XT, float>::value) {
            const float4* xp = (const float4*)(X + (size_t)nodeA * 128);
            #pragma unroll
            for (int ks = 0; ks < 4; ++ks) {
                float4 a = v ? xp[ks * 8 + quad * 2]     : make_float4(0.f, 0.f, 0.f, 0.f);
                float4 b = v ? xp[ks * 8 + quad * 2 + 1] : make_float4(0.f, 0.f, 0.f, 0.f);
                dst[ks * 8 + 0] = a.x; dst[ks * 8 + 1] = a.y;
                dst[ks * 8 + 2] = a.z; dst[ks * 8 + 3] = a.w;
                dst[ks * 8 + 4] = b.x; dst[ks * 8 + 5] = b.y;
                dst[ks * 8 + 6] = b.z; dst[ks * 8 + 7] = b.w;
            }
        } else {
            const h16x8* xp = (const h16x8*)(X + (size_t)nodeA * 128);
            #pragma unroll
            for (int ks = 0; ks < 4; ++ks) {
                h16x8 hv;
                if (v) {
                    hv = xp[ks * 4 + quad];
                } else {
                    #pragma unroll
                    for (int j = 0; j < 8; ++j) hv[j] = (_Float16)0.f;
                }
                #pragma unroll
                for (int j = 0; j < 8; ++j) dst[ks * 8 + j] = (float)hv[j];
            }
        }
    };

    loadX(tile, xr);
    while (true) {
        int next = tile + gridDim.x;
        if (next < ntiles) loadX(next, xn);

        f32x4 acc[9];
        #pragma unroll
        for (int t = 0; t < 9; ++t) acc[t] = (f32x4){0.f, 0.f, 0.f, 0.f};

        #pragma unroll
        for (int ks = 0; ks < 4; ++ks) {
            bf16x8 ahi, alo;
            #pragma unroll
            for (int j = 0; j < 8; ++j) {
                float xv = xr[ks * 8 + j];
                __bf16 h = (__bf16)xv;
                ahi[j] = h;
                alo[j] = (__bf16)(xv - (float)h);
            }
            const int kq = ks * 4 + quad;

            {
                bf16x8 bh = wext[(kq) * 16 + l15];
                bf16x8 bl = wext[(16 + kq) * 16 + l15];
                acc[8] = __builtin_amdgcn_mfma_f32_16x16x32_bf16(ahi, bh, acc[8], 0, 0, 0);
                acc[8] = __builtin_amdgcn_mfma_f32_16x16x32_bf16(alo, bh, acc[8], 0, 0, 0);
                acc[8] = __builtin_amdgcn_mfma_f32_16x16x32_bf16(ahi, bl, acc[8], 0, 0, 0);
            }
            #pragma unroll
            for (int t = 0; t < 8; ++t) {
                bf16x8 bh = lw[(kq * 8 + t) * 16 + l15];
                bf16x8 bl = lw[((16 + kq) * 8 + t) * 16 + l15];
                acc[t] = __builtin_amdgcn_mfma_f32_16x16x32_bf16(ahi, bh, acc[t], 0, 0, 0);
                acc[t] = __builtin_amdgcn_mfma_f32_16x16x32_bf16(alo, bh, acc[t], 0, 0, 0);
                acc[t] = __builtin_amdgcn_mfma_f32_16x16x32_bf16(ahi, bl, acc[t], 0, 0, 0);
            }
        }

        const int nodeC = tile * 64 + wave * 16 + quad * 4;
        #pragma unroll
        for (int r = 0; r < 4; ++r) {
            int gn = nodeC + r;
            if (gn < nnodes) {
                #pragma unroll
                for (int t = 0; t < 8; ++t)
                    featH[(size_t)gn * 128 + t * 16 + l15] = (_Float16)acc[t][r];
            }
        }
        if (l15 < 8) {
            #pragma unroll
            for (int r = 0; r < 4; ++r) {
                int gn = nodeC + r;
                if (gn < nnodes) {
                    if (l15 < 4) el[gn * HEADS + l15] = acc[8][r];
                    else         er[gn * HEADS + (l15 - 4)] = acc[8][r];
                }
            }
        }

        if (next >= ntiles) break;
        #pragma unroll
        for (int i = 0; i < 32; ++i) xr[i] = xn[i];
        tile = next;
    }
}

// ---------------------------------------------------------------------------
// Bucketed CSR build: bin = dst*8 + (src>>shift)  (8 coarse src buckets ->
// gather working set ~2 MB per bucket, per-XCD-L2-sized). hist captures
// within-bin rank from the atomic return; scatter is atomic-free.
// ---------------------------------------------------------------------------
__global__ __launch_bounds__(256) void hist_kernel(
    const int* __restrict__ src, const int* __restrict__ dst,
    int* __restrict__ counts, int* __restrict__ rank, int nedges, int shift)
{
    int i0 = (blockIdx.x * 256 + threadIdx.x) * 4;
    if (i0 + 3 < nedges) {
        int4 d = *(const int4*)&dst[i0];
        int4 s = *(const int4*)&src[i0];
        int4 r;
        r.x = atomicAdd(&counts[d.x * NBUCK + (s.x >> shift)], 1);
        r.y = atomicAdd(&counts[d.y * NBUCK + (s.y >> shift)], 1);
        r.z = atomicAdd(&counts[d.z * NBUCK + (s.z >> shift)], 1);
        r.w = atomicAdd(&counts[d.w * NBUCK + (s.w >> shift)], 1);
        *(int4*)&rank[i0] = r;
    } else {
        for (int i = i0; i < nedges; ++i)
            rank[i] = atomicAdd(&counts[dst[i] * NBUCK + (src[i] >> shift)], 1);
    }
}

__global__ __launch_bounds__(256) void scan1_kernel(
    const int* __restrict__ counts, int* __restrict__ offsets,
    int* __restrict__ bsums, int n)
{
    __shared__ int wsums[4];
    const int tid = threadIdx.x, lane = tid & 63, w = tid >> 6;
    const int i = blockIdx.x * 1024 + tid * 4;

    int4 v = make_int4(0, 0, 0, 0);
    if (i + 3 < n) v = *(const int4*)&counts[i];
    else {
        if (i < n)     v.x = counts[i];
        if (i + 1 < n) v.y = counts[i + 1];
        if (i + 2 < n) v.z = counts[i + 2];
    }
    int s0 = v.x, s1 = s0 + v.y, s2 = s1 + v.z, s3 = s2 + v.w;

    int x = s3;
    #pragma unroll
    for (int off = 1; off < 64; off <<= 1) {
        int t = __shfl_up(x, off, 64);
        if (lane >= off) x += t;
    }
    if (lane == 63) wsums[w] = x;
    __syncthreads();
    int wbase = 0;
    #pragma unroll
    for (int k = 0; k < 4; ++k) if (k < w) wbase += wsums[k];

    int tbase = wbase + x - s3;
    if (i < n)     offsets[i]     = tbase;
    if (i + 1 < n) offsets[i + 1] = tbase + s0;
    if (i + 2 < n) offsets[i + 2] = tbase + s1;
    if (i + 3 < n) offsets[i + 3] = tbase + s2;
    if (tid == 255) bsums[blockIdx.x] = wbase + x;
}

__global__ __launch_bounds__(64) void scan2_kernel(int* __restrict__ bsums, int nb)
{
    const int lane = threadIdx.x;
    int run = 0;
    for (int base = 0; base < nb; base += 64) {
        int i = base + lane;
        int v = (i < nb) ? bsums[i] : 0;
        int x = v;
        #pragma unroll
        for (int off = 1; off < 64; off <<= 1) {
            int t = __shfl_up(x, off, 64);
            if (lane >= off) x += t;
        }
        if (i < nb) bsums[i] = run + x - v;
        run += __shfl(x, 63, 64);
    }
}

__global__ __launch_bounds__(256) void scan3_kernel(
    int* __restrict__ offsets, const int* __restrict__ bsums, int n, int nedges)
{
    const int i = blockIdx.x * 1024 + threadIdx.x * 4;
    const int base = bsums[blockIdx.x];
    #pragma unroll
    for (int k = 0; k < 4; ++k)
        if (i + k < n) offsets[i + k] += base;
    if (blockIdx.x == 0 && threadIdx.x == 0) offsets[n] = nedges;
}

__global__ __launch_bounds__(256) void scatter_kernel(
    const int* __restrict__ src, const int* __restrict__ dst,
    const int* __restrict__ rank, const int* __restrict__ offsets,
    int* __restrict__ csr_src, int nedges, int shift)
{
    int i0 = (blockIdx.x * 256 + threadIdx.x) * 4;
    if (i0 + 3 < nedges) {
        int4 d = *(const int4*)&dst[i0];
        int4 r = *(const int4*)&rank[i0];
        int4 s = *(const int4*)&src[i0];
        csr_src[offsets[d.x * NBUCK + (s.x >> shift)] + r.x] = s.x;
        csr_src[offsets[d.y * NBUCK + (s.y >> shift)] + r.y] = s.y;
        csr_src[offsets[d.z * NBUCK + (s.z >> shift)] + r.z] = s.z;
        csr_src[offsets[d.w * NBUCK + (s.w >> shift)] + r.w] = s.w;
    } else {
        for (int i = i0; i < nedges; ++i)
            csr_src[offsets[dst[i] * NBUCK + (src[i] >> shift)] + rank[i]] = src[i];
    }
}

// ---------------------------------------------------------------------------
// Gather aggregation: 4 dst nodes per wave, 16 lanes/node, 8 fp16 feats/lane.
// Node n's edges = [offsets[8n], offsets[8n+8]) (bucket-contiguous).
// !MEAN writes fp16 (next layer's GEMM input); MEAN writes f32 output.
// ---------------------------------------------------------------------------
template <bool MEAN>
__global__ __launch_bounds__(256) void aggregate_kernel(
    const _Float16* __restrict__ featH, const float* __restrict__ el,
    const float* __restrict__ er, const int* __restrict__ offsets,
    const int* __restrict__ csr_src, void* __restrict__ outp, int nnodes)
{
    const int wid = (blockIdx.x * 256 + threadIdx.x) >> 6;
    const int lane = threadIdx.x & 63;
    const int g = lane >> 4, u = lane & 15, h = u >> 2;
    const int n = wid * 4 + g;
    const bool nv = n < nnodes;

    int beg = 0, end = 0;
    float ern = 0.f;
    if (nv) {
        beg = offsets[n * NBUCK];
        end = offsets[n * NBUCK + NBUCK];
        ern = er[n * HEADS + h];
    }
    int md = end - beg;
    md = max(md, __shfl_xor(md, 16, 64));
    md = max(md, __shfl_xor(md, 32, 64));

    float a[8];
    #pragma unroll
    for (int p = 0; p < 8; ++p) a[p] = 0.f;
    float sw = 0.f;

    int j = beg;
    bool v = j < end;
    int s = v ? csr_src[j] : 0;
    float q = el[s * HEADS + h];
    h16x8 f = ((const h16x8*)(featH + (size_t)s * 128))[u];

    for (int it = 0; it < md; ++it) {
        int jn = j + 1;
        bool vn = jn < end;
        int sn = vn ? csr_src[jn] : 0;
        float qn = el[sn * HEADS + h];
        h16x8 fn = ((const h16x8*)(featH + (size_t)sn * 128))[u];

        float e = q + ern;
        e = e > 0.f ? e : NEG * e;
        float w = v ? __expf(e) : 0.f;
        #pragma unroll
        for (int p = 0; p < 8; ++p) a[p] += w * (float)f[p];
        sw += w;

        j = jn; v = vn; q = qn; f = fn;
    }

    float inv = sw > 0.f ? 1.f / sw : 0.f;
    float r[8];
    #pragma unroll
    for (int p = 0; p < 8; ++p) {
        float t = a[p] * inv;
        r[p] = t > 0.f ? t : expm1f(t);
    }

    if (!MEAN) {
        if (nv) {
            h16x8 o;
            #pragma unroll
            for (int p = 0; p < 8; ++p) o[p] = (_Float16)r[p];
            ((h16x8*)outp)[(size_t)n * 16 + u] = o;
        }
    } else {
        #pragma unroll
        for (int p = 0; p < 8; ++p) {
            r[p] += __shfl_xor(r[p], 4, 64);
            r[p] += __shfl_xor(r[p], 8, 64);
        }
        if (nv && u < 4) {
            float* out = (float*)outp;
            float4* o4 = (float4*)(out + (size_t)n * 32 + u * 8);
            o4[0] = make_float4(0.25f * r[0], 0.25f * r[1], 0.25f * r[2], 0.25f * r[3]);
            o4[1] = make_float4(0.25f * r[4], 0.25f * r[5], 0.25f * r[6], 0.25f * r[7]);
        }
    }
}

// ---------------------------------------------------------------------------
extern "C" void kernel_launch(void* const* d_in, const int* in_sizes, int n_in,
                              void* d_out, int out_size, void* d_ws, size_t ws_size,
                              hipStream_t stream)
{
    const float* x   = (const float*)d_in[0];
    const int*   src = (const int*)d_in[1];
    const int*   dst = (const int*)d_in[2];
    const float* W1  = (const float*)d_in[3];
    const float* al1 = (const float*)d_in[4];
    const float* ar1 = (const float*)d_in[5];
    const float* W2  = (const float*)d_in[6];
    const float* al2 = (const float*)d_in[7];
    const float* ar2 = (const float*)d_in[8];

    const int N = in_sizes[0] / FDIM;
    const int E = in_sizes[1];
    const int NB = N * NBUCK;

    int shift = 0;
    while (((N - 1) >> shift) > (NBUCK - 1)) ++shift;

    // workspace: h1[N*128] fp16 | featH[N*128] fp16 | el[N*4] | er[N*4] |
    //   counts[8N] | offsets[8N+1] | rank[E] | csr_src[E] | bsums[512] | W imgs
    _Float16* h1 = (_Float16*)d_ws;
    _Float16* featH = h1 + (size_t)N * FDIM;
    float* el = (float*)(featH + (size_t)N * FDIM);
    float* er = el + (size_t)N * HEADS;
    int* counts  = (int*)(er + (size_t)N * HEADS);
    int* offsets = counts + NB;
    int* rank    = offsets + (NB + 1);
    int* csr_src = rank + E;
    int* bsums   = csr_src + E;
    uintptr_t wp = ((uintptr_t)(bsums + 512) + 63) & ~(uintptr_t)63;
    __bf16* wf1   = (__bf16*)wp;             // 32768 bf16
    __bf16* wext1 = wf1 + 32768;             // 4096 bf16
    __bf16* wf2   = wext1 + 4096;
    __bf16* wext2 = wf2 + 32768;

    const int ntiles = (N + 63) / 64;
    const int gemm_grid = ntiles < 256 ? ntiles : 256;
    const int edge4_grid = ((E + 3) / 4 + 255) / 256;
    const int agg_grid  = ((N + 3) / 4 + 3) / 4;   // 4 nodes/wave, 4 waves/block
    const int nscan     = (NB + 1023) / 1024;

    // ---- W preprocessing (one dispatch) ----
    prep_kernel<<<258, 256, 0, stream>>>(W1, al1, ar1, W2, al2, ar2,
                                         wf1, wext1, wf2, wext2);

    // ---- bucketed CSR build (once; shared by both layers) ----
    (void)hipMemsetAsync(counts, 0, (size_t)NB * sizeof(int), stream);
    hist_kernel<<<edge4_grid, 256, 0, stream>>>(src, dst, counts, rank, E, shift);
    scan1_kernel<<<nscan, 256, 0, stream>>>(counts, offsets, bsums, NB);
    scan2_kernel<<<1, 64, 0, stream>>>(bsums, nscan);
    scan3_kernel<<<nscan, 256, 0, stream>>>(offsets, bsums, NB, E);
    scatter_kernel<<<edge4_grid, 256, 0, stream>>>(src, dst, rank, offsets,
                                                   csr_src, E, shift);

    // ---- layer 1 ----
    gemm_mfma_kernel<float><<<gemm_grid, 256, 0, stream>>>(
        x, (const bf16x8*)wf1, (const bf16x8*)wext1, featH, el, er, N, ntiles);
    aggregate_kernel<false><<<agg_grid, 256, 0, stream>>>(
        featH, el, er, offsets, csr_src, (void*)h1, N);

    // ---- layer 2 ----
    gemm_mfma_kernel<_Float16><<<gemm_grid, 256, 0, stream>>>(
        h1, (const bf16x8*)wf2, (const bf16x8*)wext2, featH, el, er, N, ntiles);
    aggregate_kernel<true><<<agg_grid, 256, 0, stream>>>(
        featH, el, er, offsets, csr_src, d_out, N);
}